// Round 12
// baseline (939.666 us; speedup 1.0000x reference)
//
#include <hip/hip_runtime.h>
#include <hip/hip_bf16.h>

// B=4, T=1024, E=1024, H=16, D=64, P=257.  Slot s = b*16+h (64 slots).
// Quirk: score slot m uses rel-K of slot pm=(m&15)*4+(m>>4); attn of slot m
// feeds w2 output of slot m2=(m&3)*16+(m>>2).
// R12: projection GEMMs get (a) unpadded 64B LDS rows (staging writes and
// frag reads both wave-contiguous -> conflict-free; R11 had 6.29M conflicts
// from the 96B stride), (b) register double-buffer prefetch of the next
// K-tile (hides global latency behind MFMA), (c) k_gemm_o retiled to 128x64
// -> 512 blocks = 2/CU.  k_fused / k_prep unchanged from R11.

typedef __attribute__((ext_vector_type(8))) short short8;
typedef __attribute__((ext_vector_type(4))) float f32x4;

__device__ __forceinline__ float bf16f(unsigned int u) {
    union { unsigned int i; float f; } v; v.i = u << 16; return v.f;
}
__device__ __forceinline__ unsigned short f2b(float x) {
    __hip_bfloat16 h = __float2bfloat16(x);
    return *reinterpret_cast<unsigned short*>(&h);
}

// ---------------------------------------------------------------------------
// K0: prep.  z=0..4: split fp32 -> (hi,lo) bf16 for hs/Wq/Wk/Wv/Wo.
// z=5 (block 0): relkB bf16 [272][64], relvT bf16 relv^T [64][264].
// ---------------------------------------------------------------------------
__global__ __launch_bounds__(256) void k_prep(
    const float* __restrict__ hs, const float* __restrict__ Wq,
    const float* __restrict__ Wk, const float* __restrict__ Wv,
    const float* __restrict__ Wo, const float* __restrict__ relk,
    const float* __restrict__ relv,
    unsigned short* __restrict__ hh, unsigned short* __restrict__ hl,
    unsigned short* __restrict__ wqh, unsigned short* __restrict__ wql,
    unsigned short* __restrict__ wkh, unsigned short* __restrict__ wkl,
    unsigned short* __restrict__ wvh, unsigned short* __restrict__ wvl,
    unsigned short* __restrict__ woh, unsigned short* __restrict__ wol,
    unsigned short* __restrict__ relkB, unsigned short* __restrict__ relvT)
{
    const int z = blockIdx.y;
    const int tid = threadIdx.x;
    if (z < 5) {
        const float* src = (z == 0) ? hs : (z == 1) ? Wq : (z == 2) ? Wk
                         : (z == 3) ? Wv : Wo;
        unsigned short* hi = (z == 0) ? hh : (z == 1) ? wqh : (z == 2) ? wkh
                           : (z == 3) ? wvh : woh;
        unsigned short* lo = (z == 0) ? hl : (z == 1) ? wql : (z == 2) ? wkl
                           : (z == 3) ? wvl : wol;
        const int n4 = (z == 0) ? 1048576 : 262144;
        const int stride = gridDim.x * 256;
        for (int i = blockIdx.x * 256 + tid; i < n4; i += stride) {
            float4 x = *(const float4*)(src + i*4);
            unsigned short h[4], l[4];
            float xs[4] = {x.x, x.y, x.z, x.w};
            #pragma unroll
            for (int j = 0; j < 4; ++j) {
                h[j] = f2b(xs[j]);
                l[j] = f2b(xs[j] - bf16f(h[j]));
            }
            *(ushort4*)(hi + i*4) = make_ushort4(h[0], h[1], h[2], h[3]);
            *(ushort4*)(lo + i*4) = make_ushort4(l[0], l[1], l[2], l[3]);
        }
    } else if (blockIdx.x == 0) {
        for (int i = tid; i < 272*64; i += 256) {
            int j = i >> 6;
            relkB[i] = (j < 257) ? f2b(relk[i]) : (unsigned short)0;
        }
        int d = tid >> 2, grp = tid & 3;
        for (int jj = 0; jj < 66; ++jj) {
            int j = grp*66 + jj;
            if (j < 264)
                relvT[d*264 + j] = (j < 257) ? f2b(relv[j*64 + d]) : (unsigned short)0;
        }
    }
}

// ---------------------------------------------------------------------------
// K1: QKV projection, split-bf16 MFMA, unpadded LDS + reg double-buffer.
// ---------------------------------------------------------------------------
__global__ __launch_bounds__(256) void k_gemm_qkv(
    const unsigned short* __restrict__ hh, const unsigned short* __restrict__ hl,
    const unsigned short* __restrict__ wqh, const unsigned short* __restrict__ wql,
    const unsigned short* __restrict__ wkh, const unsigned short* __restrict__ wkl,
    const unsigned short* __restrict__ wvh, const unsigned short* __restrict__ wvl,
    const float* __restrict__ bq, const float* __restrict__ bk,
    const float* __restrict__ bv,
    unsigned short* __restrict__ qb, unsigned short* __restrict__ kb,
    unsigned short* __restrict__ vt)
{
    __shared__ __align__(16) unsigned short sAh[128][32];
    __shared__ __align__(16) unsigned short sAl[128][32];
    __shared__ __align__(16) unsigned short sBh[128][32];
    __shared__ __align__(16) unsigned short sBl[128][32];
    const int tid = threadIdx.x;
    const int eb = blockIdx.x * 128, nb = blockIdx.y * 128, z = blockIdx.z;
    const unsigned short* Bh = (z == 0) ? wqh : (z == 1) ? wkh : wvh;
    const unsigned short* Bl = (z == 0) ? wql : (z == 1) ? wkl : wvl;
    const float* bias = (z == 0) ? bq : (z == 1) ? bk : bv;
    const float scale = (z == 0) ? 0.125f : 1.0f;
    const int w = tid >> 6, lane = tid & 63, lq = lane & 15, quad = lane >> 4;
    const int wr = w >> 1, wc = w & 1;
    const int srow = tid >> 2, sc8 = (tid & 3) * 8;

    f32x4 acc[4][4];
    #pragma unroll
    for (int i = 0; i < 4; ++i)
        #pragma unroll
        for (int j = 0; j < 4; ++j) acc[i][j] = (f32x4){0,0,0,0};

    uint4 st[8];
    st[0] = *(const uint4*)(hh + (size_t)(nb + srow) * 1024 + sc8);
    st[1] = *(const uint4*)(hh + (size_t)(nb + srow + 64) * 1024 + sc8);
    st[2] = *(const uint4*)(hl + (size_t)(nb + srow) * 1024 + sc8);
    st[3] = *(const uint4*)(hl + (size_t)(nb + srow + 64) * 1024 + sc8);
    st[4] = *(const uint4*)(Bh + (size_t)(eb + srow) * 1024 + sc8);
    st[5] = *(const uint4*)(Bh + (size_t)(eb + srow + 64) * 1024 + sc8);
    st[6] = *(const uint4*)(Bl + (size_t)(eb + srow) * 1024 + sc8);
    st[7] = *(const uint4*)(Bl + (size_t)(eb + srow + 64) * 1024 + sc8);

    for (int k0 = 0; k0 < 1024; k0 += 32) {
        __syncthreads();   // prev-iter frag reads done
        *(uint4*)&sAh[srow][sc8] = st[0];  *(uint4*)&sAh[srow + 64][sc8] = st[1];
        *(uint4*)&sAl[srow][sc8] = st[2];  *(uint4*)&sAl[srow + 64][sc8] = st[3];
        *(uint4*)&sBh[srow][sc8] = st[4];  *(uint4*)&sBh[srow + 64][sc8] = st[5];
        *(uint4*)&sBl[srow][sc8] = st[6];  *(uint4*)&sBl[srow + 64][sc8] = st[7];
        uint4 nx[8];
        if (k0 < 992) {
            const int kn = k0 + 32;
            nx[0] = *(const uint4*)(hh + (size_t)(nb + srow) * 1024 + kn + sc8);
            nx[1] = *(const uint4*)(hh + (size_t)(nb + srow + 64) * 1024 + kn + sc8);
            nx[2] = *(const uint4*)(hl + (size_t)(nb + srow) * 1024 + kn + sc8);
            nx[3] = *(const uint4*)(hl + (size_t)(nb + srow + 64) * 1024 + kn + sc8);
            nx[4] = *(const uint4*)(Bh + (size_t)(eb + srow) * 1024 + kn + sc8);
            nx[5] = *(const uint4*)(Bh + (size_t)(eb + srow + 64) * 1024 + kn + sc8);
            nx[6] = *(const uint4*)(Bl + (size_t)(eb + srow) * 1024 + kn + sc8);
            nx[7] = *(const uint4*)(Bl + (size_t)(eb + srow + 64) * 1024 + kn + sc8);
        }
        __syncthreads();   // tile staged

        short8 ah[4], al[4], bhf[4], blf[4];
        #pragma unroll
        for (int t = 0; t < 4; ++t) {
            ah[t]  = *(const short8*)&sAh[wr*64 + t*16 + lq][quad*8];
            al[t]  = *(const short8*)&sAl[wr*64 + t*16 + lq][quad*8];
            bhf[t] = *(const short8*)&sBh[wc*64 + t*16 + lq][quad*8];
            blf[t] = *(const short8*)&sBl[wc*64 + t*16 + lq][quad*8];
        }
        #pragma unroll
        for (int ti = 0; ti < 4; ++ti)
            #pragma unroll
            for (int tj = 0; tj < 4; ++tj) {
                acc[ti][tj] = __builtin_amdgcn_mfma_f32_16x16x32_bf16(ah[ti], bhf[tj], acc[ti][tj], 0, 0, 0);
                acc[ti][tj] = __builtin_amdgcn_mfma_f32_16x16x32_bf16(al[ti], bhf[tj], acc[ti][tj], 0, 0, 0);
                acc[ti][tj] = __builtin_amdgcn_mfma_f32_16x16x32_bf16(ah[ti], blf[tj], acc[ti][tj], 0, 0, 0);
            }
        if (k0 < 992) {
            #pragma unroll
            for (int i = 0; i < 8; ++i) st[i] = nx[i];
        }
    }

    #pragma unroll
    for (int tj = 0; tj < 4; ++tj) {
        int e = eb + wc*64 + tj*16 + lq;
        float bb = bias[e];
        int h = e >> 6, d = e & 63;
        #pragma unroll
        for (int ti = 0; ti < 4; ++ti) {
            #pragma unroll
            for (int i = 0; i < 4; ++i) {
                int n = nb + wr*64 + ti*16 + quad*4 + i;
                int bidx = n >> 10, t = n & 1023;
                int s = bidx*16 + h;
                float val = (acc[ti][tj][i] + bb) * scale;
                if (z == 2)
                    vt[(((size_t)(s*64 + d)) << 10) + t] = f2b(val);
                else if (z == 0)
                    qb[(((size_t)(s*1024 + t)) << 6) + d] = f2b(val);
                else
                    kb[(((size_t)(s*1024 + t)) << 6) + d] = f2b(val);
            }
        }
    }
}

// ---------------------------------------------------------------------------
// K2: MFMA flash attention (unchanged from R11).
// ---------------------------------------------------------------------------
__global__ __launch_bounds__(256) void k_fused(
    const unsigned short* __restrict__ qb, const unsigned short* __restrict__ kb,
    const unsigned short* __restrict__ vt, const unsigned short* __restrict__ relkB,
    const unsigned short* __restrict__ relvT, const float* __restrict__ relv,
    float* __restrict__ c1, float* __restrict__ c2)
{
    __shared__ __align__(16) unsigned short sP[2][2][16][72];
    __shared__ __align__(16) unsigned short sG[2][16][104];
    __shared__ unsigned short sR[32][273];
    __shared__ float sRed[4][3][32];

    const int tid = threadIdx.x;
    const int m  = blockIdx.y;
    const int q0 = blockIdx.x * 32;
    const int pm = (m & 15) * 4 + (m >> 4);
    const int m2 = (m & 3) * 16 + (m >> 2);
    const int w    = tid >> 6;
    const int lane = tid & 63;
    const int lq   = lane & 15;
    const int quad = lane >> 4;

    #pragma unroll
    for (int sub = 0; sub < 2; ++sub) {
        const unsigned short* qpm = qb + (((size_t)(pm*1024 + q0 + sub*16 + lq)) << 6);
        short8 a0 = *(const short8*)(qpm + quad*8);
        short8 a1 = *(const short8*)(qpm + 32 + quad*8);
        for (int jt = w; jt < 17; jt += 4) {
            const unsigned short* rkb = relkB + (size_t)(jt*16 + lq) * 64;
            short8 b0 = *(const short8*)(rkb + quad*8);
            short8 b1 = *(const short8*)(rkb + 32 + quad*8);
            f32x4 cr = {0,0,0,0};
            cr = __builtin_amdgcn_mfma_f32_16x16x32_bf16(a0, b0, cr, 0, 0, 0);
            cr = __builtin_amdgcn_mfma_f32_16x16x32_bf16(a1, b1, cr, 0, 0, 0);
            #pragma unroll
            for (int i = 0; i < 4; ++i)
                sR[sub*16 + quad*4 + i][jt*16 + lq] = f2b(cr[i]);
        }
    }
    __syncthreads();

    short8 aq0[2], aq1[2];
    #pragma unroll
    for (int sub = 0; sub < 2; ++sub) {
        const unsigned short* qm = qb + (((size_t)(m*1024 + q0 + sub*16 + lq)) << 6);
        aq0[sub] = *(const short8*)(qm + quad*8);
        aq1[sub] = *(const short8*)(qm + 32 + quad*8);
    }
    const float relE0 = relv[w*16 + lq];
    const float relE1 = relv[256*64 + w*16 + lq];

    float lsum[2][4], slow[2][4], shigh[2][4];
    f32x4 c1a[2], c2a[2];
    #pragma unroll
    for (int sub = 0; sub < 2; ++sub) {
        c1a[sub] = (f32x4){0,0,0,0};
        c2a[sub] = (f32x4){0,0,0,0};
        #pragma unroll
        for (int i = 0; i < 4; ++i) {
            lsum[sub][i] = 0.0f; slow[sub][i] = 0.0f; shigh[sub][i] = 0.0f;
        }
    }

    const unsigned short* kbase = kb + (((size_t)(m*1024 + w*16 + lq)) << 6);
    const unsigned short* vbase = vt + (((size_t)(m*64 + w*16 + lq)) << 10);
    short8 ck0 = *(const short8*)(kbase + quad*8);
    short8 ck1 = *(const short8*)(kbase + 32 + quad*8);
    short8 cv0 = *(const short8*)(vbase + quad*8);
    short8 cv1 = *(const short8*)(vbase + 32 + quad*8);

    #pragma unroll 1
    for (int kt = 0; kt < 16; ++kt) {
        const int k0 = kt * 64;
        const int dmin = q0 - k0 - 63;
        const int dmax = q0 + 31 - k0;
        const bool needG = (dmax >= -127) && (dmin <= 127);
        const int buf = kt & 1;

        short8 nk0 = ck0, nk1 = ck1, nv0 = cv0, nv1 = cv1;
        if (kt < 15) {
            const size_t ko = (size_t)(k0 + 64);
            nk0 = *(const short8*)(kbase + (ko << 6) + quad*8);
            nk1 = *(const short8*)(kbase + (ko << 6) + 32 + quad*8);
            nv0 = *(const short8*)(vbase + ko + quad*8);
            nv1 = *(const short8*)(vbase + ko + 32 + quad*8);
        }

        f32x4 s4[2];
        #pragma unroll
        for (int sub = 0; sub < 2; ++sub) {
            s4[sub] = (f32x4){0,0,0,0};
            s4[sub] = __builtin_amdgcn_mfma_f32_16x16x32_bf16(aq0[sub], ck0, s4[sub], 0, 0, 0);
            s4[sub] = __builtin_amdgcn_mfma_f32_16x16x32_bf16(aq1[sub], ck1, s4[sub], 0, 0, 0);
        }

        const int kcol = k0 + w*16 + lq;
        float e[2][4];
        #pragma unroll
        for (int sub = 0; sub < 2; ++sub) {
            #pragma unroll
            for (int i = 0; i < 4; ++i) {
                int row = sub*16 + quad*4 + i;
                int dist = (q0 + row) - kcol;
                int jd = dist < -128 ? 0 : (dist > 128 ? 256 : dist + 128);
                float ev = exp2f((s4[sub][i] + bf16f(sR[row][jd])) * 1.44269504f);
                e[sub][i] = ev;
                lsum[sub][i] += ev;
                if (dist <= -128)     slow[sub][i]  += ev;
                else if (dist >= 128) shigh[sub][i] += ev;
                sP[buf][sub][quad*4 + i][w*16 + lq] = f2b(ev);
            }
        }
        if (needG) {
            #pragma unroll
            for (int i = 0; i < 7; ++i) {
                int idx = tid + i * 256;
                if (idx < 1664) ((unsigned int*)sG)[idx] = 0u;
            }
        }
        __syncthreads();

        if (needG) {
            #pragma unroll
            for (int sub = 0; sub < 2; ++sub) {
                int jminb = q0 + sub*16 - k0 - 63;
                jminb = (jminb < -127 ? -127 : jminb) + 128;
                int jlo8 = jminb & ~7;
                if (jlo8 > 160) jlo8 = 160;
                #pragma unroll
                for (int i = 0; i < 4; ++i) {
                    int row = sub*16 + quad*4 + i;
                    int dist = (q0 + row) - kcol;
                    if (dist > -128 && dist < 128)
                        sG[sub][quad*4 + i][dist + 128 - jlo8] = f2b(e[sub][i]);
                }
            }
        }

        #pragma unroll
        for (int sub = 0; sub < 2; ++sub) {
            short8 ap0 = *(const short8*)&sP[buf][sub][lq][quad*8];
            short8 ap1 = *(const short8*)&sP[buf][sub][lq][32 + quad*8];
            c1a[sub] = __builtin_amdgcn_mfma_f32_16x16x32_bf16(ap0, cv0, c1a[sub], 0, 0, 0);
            c1a[sub] = __builtin_amdgcn_mfma_f32_16x16x32_bf16(ap1, cv1, c1a[sub], 0, 0, 0);
        }

        if (needG) {
            __syncthreads();
            #pragma unroll
            for (int sub = 0; sub < 2; ++sub) {
                int jminb = q0 + sub*16 - k0 - 63;
                jminb = (jminb < -127 ? -127 : jminb) + 128;
                int jlo8 = jminb & ~7;
                if (jlo8 > 160) jlo8 = 160;
                short8 ag0 = *(const short8*)&sG[sub][lq][quad*8];
                short8 ag1 = *(const short8*)&sG[sub][lq][32 + quad*8];
                short8 ag2 = *(const short8*)&sG[sub][lq][64 + quad*8];
                const unsigned short* rrow = relvT + (size_t)(w*16 + lq) * 264 + jlo8;
                short8 br0 = *(const short8*)(rrow + quad*8);
                short8 br1 = *(const short8*)(rrow + 32 + quad*8);
                short8 br2 = *(const short8*)(rrow + 64 + quad*8);
                c2a[sub] = __builtin_amdgcn_mfma_f32_16x16x32_bf16(ag0, br0, c2a[sub], 0, 0, 0);
                c2a[sub] = __builtin_amdgcn_mfma_f32_16x16x32_bf16(ag1, br1, c2a[sub], 0, 0, 0);
                c2a[sub] = __builtin_amdgcn_mfma_f32_16x16x32_bf16(ag2, br2, c2a[sub], 0, 0, 0);
            }
            __syncthreads();
        }

        ck0 = nk0; ck1 = nk1; cv0 = nv0; cv1 = nv1;
    }

    #pragma unroll
    for (int off = 1; off < 16; off <<= 1) {
        #pragma unroll
        for (int sub = 0; sub < 2; ++sub)
            #pragma unroll
            for (int i = 0; i < 4; ++i) {
                lsum[sub][i]  += __shfl_xor(lsum[sub][i],  off, 64);
                slow[sub][i]  += __shfl_xor(slow[sub][i],  off, 64);
                shigh[sub][i] += __shfl_xor(shigh[sub][i], off, 64);
            }
    }
    if (lq == 0) {
        #pragma unroll
        for (int sub = 0; sub < 2; ++sub)
            #pragma unroll
            for (int i = 0; i < 4; ++i) {
                int row = sub*16 + quad*4 + i;
                sRed[w][0][row] = lsum[sub][i];
                sRed[w][1][row] = slow[sub][i];
                sRed[w][2][row] = shigh[sub][i];
            }
    }
    __syncthreads();

    const int b1 = m >> 4,  h1 = m & 15;
    const int b2 = m2 >> 4, h2 = m2 & 15;
    #pragma unroll
    for (int sub = 0; sub < 2; ++sub) {
        #pragma unroll
        for (int i = 0; i < 4; ++i) {
            int row = sub*16 + quad*4 + i;
            float lt = sRed[0][0][row] + sRed[1][0][row] + sRed[2][0][row] + sRed[3][0][row];
            float sl = sRed[0][1][row] + sRed[1][1][row] + sRed[2][1][row] + sRed[3][1][row];
            float sh = sRed[0][2][row] + sRed[1][2][row] + sRed[2][2][row] + sRed[3][2][row];
            float c2v = c2a[sub][i] + sl * relE0 + sh * relE1;
            float inv = 1.0f / lt;
            int col = w*16 + lq;
            c1[(size_t)(b1*1024 + q0 + row) * 1024 + h1*64 + col] = c1a[sub][i] * inv;
            c2[(size_t)(b2*1024 + q0 + row) * 1024 + h2*64 + col] = c2v * inv;
        }
    }
}

// ---------------------------------------------------------------------------
// K3: out = (c1+c2) @ Wo^T + bo, split-bf16 MFMA, 128x64 tile (512 blocks),
// unpadded LDS + reg double-buffer.
// ---------------------------------------------------------------------------
__global__ __launch_bounds__(256) void k_gemm_o(
    const float* __restrict__ c1, const float* __restrict__ c2,
    const unsigned short* __restrict__ woh, const unsigned short* __restrict__ wol,
    const float* __restrict__ bo, float* __restrict__ outp)
{
    __shared__ __align__(16) unsigned short sAh[128][32];
    __shared__ __align__(16) unsigned short sAl[128][32];
    __shared__ __align__(16) unsigned short sBh[64][32];
    __shared__ __align__(16) unsigned short sBl[64][32];
    const int tid = threadIdx.x;
    const int eb = blockIdx.x * 64, nb = blockIdx.y * 128;
    const int w = tid >> 6, lane = tid & 63, lq = lane & 15, quad = lane >> 4;
    const int wr = w >> 1, wc = w & 1;
    const int srow = tid >> 2, sc8 = (tid & 3) * 8;

    f32x4 acc[4][2];
    #pragma unroll
    for (int i = 0; i < 4; ++i)
        #pragma unroll
        for (int j = 0; j < 2; ++j) acc[i][j] = (f32x4){0,0,0,0};

    float4 fa[8]; uint4 sb[2];
    {
        size_t o0 = (size_t)(nb + srow) * 1024 + sc8;
        size_t o1 = (size_t)(nb + srow + 64) * 1024 + sc8;
        fa[0] = *(const float4*)(c1 + o0); fa[1] = *(const float4*)(c1 + o0 + 4);
        fa[2] = *(const float4*)(c2 + o0); fa[3] = *(const float4*)(c2 + o0 + 4);
        fa[4] = *(const float4*)(c1 + o1); fa[5] = *(const float4*)(c1 + o1 + 4);
        fa[6] = *(const float4*)(c2 + o1); fa[7] = *(const float4*)(c2 + o1 + 4);
        sb[0] = *(const uint4*)(woh + (size_t)(eb + srow) * 1024 + sc8);
        sb[1] = *(const uint4*)(wol + (size_t)(eb + srow) * 1024 + sc8);
    }

    for (int k0 = 0; k0 < 1024; k0 += 32) {
        __syncthreads();
        #pragma unroll
        for (int r2 = 0; r2 < 2; ++r2) {
            const float* x0 = (const float*)&fa[r2*4 + 0];
            const float* x1 = (const float*)&fa[r2*4 + 1];
            const float* y0 = (const float*)&fa[r2*4 + 2];
            const float* y1 = (const float*)&fa[r2*4 + 3];
            unsigned short hh8[8], ll8[8];
            #pragma unroll
            for (int j = 0; j < 4; ++j) {
                float v0 = x0[j] + y0[j];
                float v1 = x1[j] + y1[j];
                hh8[j]   = f2b(v0);  ll8[j]   = f2b(v0 - bf16f(hh8[j]));
                hh8[4+j] = f2b(v1);  ll8[4+j] = f2b(v1 - bf16f(hh8[4+j]));
            }
            *(uint4*)&sAh[srow + r2*64][sc8] = *(const uint4*)hh8;
            *(uint4*)&sAl[srow + r2*64][sc8] = *(const uint4*)ll8;
        }
        *(uint4*)&sBh[srow][sc8] = sb[0];
        *(uint4*)&sBl[srow][sc8] = sb[1];

        float4 nfa[8]; uint4 nsb[2];
        if (k0 < 992) {
            const int kn = k0 + 32;
            size_t o0 = (size_t)(nb + srow) * 1024 + kn + sc8;
            size_t o1 = (size_t)(nb + srow + 64) * 1024 + kn + sc8;
            nfa[0] = *(const float4*)(c1 + o0); nfa[1] = *(const float4*)(c1 + o0 + 4);
            nfa[2] = *(const float4*)(c2 + o0); nfa[3] = *(const float4*)(c2 + o0 + 4);
            nfa[4] = *(const float4*)(c1 + o1); nfa[5] = *(const float4*)(c1 + o1 + 4);
            nfa[6] = *(const float4*)(c2 + o1); nfa[7] = *(const float4*)(c2 + o1 + 4);
            nsb[0] = *(const uint4*)(woh + (size_t)(eb + srow) * 1024 + kn + sc8);
            nsb[1] = *(const uint4*)(wol + (size_t)(eb + srow) * 1024 + kn + sc8);
        }
        __syncthreads();

        short8 ah[4], al[4], bhf[2], blf[2];
        #pragma unroll
        for (int t = 0; t < 4; ++t) {
            ah[t] = *(const short8*)&sAh[wr*64 + t*16 + lq][quad*8];
            al[t] = *(const short8*)&sAl[wr*64 + t*16 + lq][quad*8];
        }
        #pragma unroll
        for (int t = 0; t < 2; ++t) {
            bhf[t] = *(const short8*)&sBh[wc*32 + t*16 + lq][quad*8];
            blf[t] = *(const short8*)&sBl[wc*32 + t*16 + lq][quad*8];
        }
        #pragma unroll
        for (int ti = 0; ti < 4; ++ti)
            #pragma unroll
            for (int tj = 0; tj < 2; ++tj) {
                acc[ti][tj] = __builtin_amdgcn_mfma_f32_16x16x32_bf16(ah[ti], bhf[tj], acc[ti][tj], 0, 0, 0);
                acc[ti][tj] = __builtin_amdgcn_mfma_f32_16x16x32_bf16(al[ti], bhf[tj], acc[ti][tj], 0, 0, 0);
                acc[ti][tj] = __builtin_amdgcn_mfma_f32_16x16x32_bf16(ah[ti], blf[tj], acc[ti][tj], 0, 0, 0);
            }
        if (k0 < 992) {
            #pragma unroll
            for (int i = 0; i < 8; ++i) fa[i] = nfa[i];
            sb[0] = nsb[0]; sb[1] = nsb[1];
        }
    }

    #pragma unroll
    for (int tj = 0; tj < 2; ++tj) {
        int e = eb + wc*32 + tj*16 + lq;
        float bb = bo[e];
        #pragma unroll
        for (int ti = 0; ti < 4; ++ti) {
            #pragma unroll
            for (int i = 0; i < 4; ++i) {
                int n = nb + wr*64 + ti*16 + quad*4 + i;
                outp[(size_t)n * 1024 + e] = acc[ti][tj][i] + bb;
            }
        }
    }
}

// ---------------------------------------------------------------------------
extern "C" void kernel_launch(void* const* d_in, const int* in_sizes, int n_in,
                              void* d_out, int out_size, void* d_ws, size_t ws_size,
                              hipStream_t stream) {
    const float* hs   = (const float*)d_in[0];
    const float* Wq   = (const float*)d_in[1];
    const float* bq   = (const float*)d_in[2];
    const float* Wk   = (const float*)d_in[3];
    const float* bk   = (const float*)d_in[4];
    const float* Wv   = (const float*)d_in[5];
    const float* bv   = (const float*)d_in[6];
    const float* Wo   = (const float*)d_in[7];
    const float* bo   = (const float*)d_in[8];
    const float* relk = (const float*)d_in[9];
    const float* relv = (const float*)d_in[10];
    float* out = (float*)d_out;

    unsigned short* wsu = (unsigned short*)d_ws;
    unsigned short* qbp   = wsu;
    unsigned short* kbp   = wsu + 4194304;
    unsigned short* vtp   = wsu + 8388608;
    unsigned short* relkB = wsu + 12582912;
    unsigned short* relvT = wsu + 12600320;
    float* c1 = (float*)(wsu + 12617360);
    float* c2 = c1 + 4194304;
    unsigned short* hh  = wsu + 29394576;
    unsigned short* hl  = hh + 4194304;
    unsigned short* wqh = hl + 4194304;
    unsigned short* wql = wqh + 1048576;
    unsigned short* wkh = wql + 1048576;
    unsigned short* wkl = wkh + 1048576;
    unsigned short* wvh = wkl + 1048576;
    unsigned short* wvl = wvh + 1048576;
    unsigned short* woh = wvl + 1048576;
    unsigned short* wol = woh + 1048576;

    k_prep<<<dim3(512, 6), 256, 0, stream>>>(hs, Wq, Wk, Wv, Wo, relk, relv,
                                             hh, hl, wqh, wql, wkh, wkl,
                                             wvh, wvl, woh, wol, relkB, relvT);
    k_gemm_qkv<<<dim3(8, 32, 3), 256, 0, stream>>>(hh, hl, wqh, wql, wkh, wkl,
                                                   wvh, wvl, bq, bk, bv,
                                                   qbp, kbp, vtp);
    k_fused<<<dim3(32, 64), 256, 0, stream>>>(qbp, kbp, vtp, relkB, relvT, relv, c1, c2);
    k_gemm_o<<<dim3(16, 32), 256, 0, stream>>>(c1, c2, woh, wol, bo, out);
}

// Round 13
// 443.201 us; speedup vs baseline: 2.1202x; 2.1202x over previous
//
#include <hip/hip_runtime.h>
#include <hip/hip_bf16.h>

// B=4, T=1024, E=1024, H=16, D=64, P=257.  Slot s = b*16+h (64 slots).
// Quirk: score slot m uses rel-K of slot pm=(m&15)*4+(m>>4); attn of slot m
// feeds w2 output of slot m2=(m&3)*16+(m>>2).
// R13: R12's register double-buffer SPILLED (WRITE 1.56GB scratch, 940us).
// Revert k_gemm_o/k_fused/k_prep to R11.  k_gemm_qkv stages via
// __builtin_amdgcn_global_load_lds width=16 (async, no VGPR round-trip):
// unpadded 64B LDS rows make the staging exactly wave-base + lane*16.

typedef __attribute__((ext_vector_type(8))) short short8;
typedef __attribute__((ext_vector_type(4))) float f32x4;

__device__ __forceinline__ float bf16f(unsigned int u) {
    union { unsigned int i; float f; } v; v.i = u << 16; return v.f;
}
__device__ __forceinline__ unsigned short f2b(float x) {
    __hip_bfloat16 h = __float2bfloat16(x);
    return *reinterpret_cast<unsigned short*>(&h);
}
__device__ __forceinline__ void gl_lds16(const unsigned short* g, unsigned short* l) {
    __builtin_amdgcn_global_load_lds(
        (const __attribute__((address_space(1))) void*)g,
        (__attribute__((address_space(3))) void*)l, 16, 0, 0);
}

// ---------------------------------------------------------------------------
// K0: prep (R11).  z=0..4: split fp32 -> (hi,lo) bf16.  z=5: rel tables.
// ---------------------------------------------------------------------------
__global__ __launch_bounds__(256) void k_prep(
    const float* __restrict__ hs, const float* __restrict__ Wq,
    const float* __restrict__ Wk, const float* __restrict__ Wv,
    const float* __restrict__ Wo, const float* __restrict__ relk,
    const float* __restrict__ relv,
    unsigned short* __restrict__ hh, unsigned short* __restrict__ hl,
    unsigned short* __restrict__ wqh, unsigned short* __restrict__ wql,
    unsigned short* __restrict__ wkh, unsigned short* __restrict__ wkl,
    unsigned short* __restrict__ wvh, unsigned short* __restrict__ wvl,
    unsigned short* __restrict__ woh, unsigned short* __restrict__ wol,
    unsigned short* __restrict__ relkB, unsigned short* __restrict__ relvT)
{
    const int z = blockIdx.y;
    const int tid = threadIdx.x;
    if (z < 5) {
        const float* src = (z == 0) ? hs : (z == 1) ? Wq : (z == 2) ? Wk
                         : (z == 3) ? Wv : Wo;
        unsigned short* hi = (z == 0) ? hh : (z == 1) ? wqh : (z == 2) ? wkh
                           : (z == 3) ? wvh : woh;
        unsigned short* lo = (z == 0) ? hl : (z == 1) ? wql : (z == 2) ? wkl
                           : (z == 3) ? wvl : wol;
        const int n4 = (z == 0) ? 1048576 : 262144;
        const int stride = gridDim.x * 256;
        for (int i = blockIdx.x * 256 + tid; i < n4; i += stride) {
            float4 x = *(const float4*)(src + i*4);
            unsigned short h[4], l[4];
            float xs[4] = {x.x, x.y, x.z, x.w};
            #pragma unroll
            for (int j = 0; j < 4; ++j) {
                h[j] = f2b(xs[j]);
                l[j] = f2b(xs[j] - bf16f(h[j]));
            }
            *(ushort4*)(hi + i*4) = make_ushort4(h[0], h[1], h[2], h[3]);
            *(ushort4*)(lo + i*4) = make_ushort4(l[0], l[1], l[2], l[3]);
        }
    } else if (blockIdx.x == 0) {
        for (int i = tid; i < 272*64; i += 256) {
            int j = i >> 6;
            relkB[i] = (j < 257) ? f2b(relk[i]) : (unsigned short)0;
        }
        int d = tid >> 2, grp = tid & 3;
        for (int jj = 0; jj < 66; ++jj) {
            int j = grp*66 + jj;
            if (j < 264)
                relvT[d*264 + j] = (j < 257) ? f2b(relv[j*64 + d]) : (unsigned short)0;
        }
    }
}

// ---------------------------------------------------------------------------
// K1: QKV projection, split-bf16 MFMA, async global_load_lds staging.
// Unpadded [128][32]-short LDS: lane l of wave w writes base(w)+16*l bytes,
// exactly the HW global_load_lds pattern.  No staging registers -> no spill.
// ---------------------------------------------------------------------------
__global__ __launch_bounds__(256) void k_gemm_qkv(
    const unsigned short* __restrict__ hh, const unsigned short* __restrict__ hl,
    const unsigned short* __restrict__ wqh, const unsigned short* __restrict__ wql,
    const unsigned short* __restrict__ wkh, const unsigned short* __restrict__ wkl,
    const unsigned short* __restrict__ wvh, const unsigned short* __restrict__ wvl,
    const float* __restrict__ bq, const float* __restrict__ bk,
    const float* __restrict__ bv,
    unsigned short* __restrict__ qb, unsigned short* __restrict__ kb,
    unsigned short* __restrict__ vt)
{
    __shared__ __align__(16) unsigned short sAh[128][32];
    __shared__ __align__(16) unsigned short sAl[128][32];
    __shared__ __align__(16) unsigned short sBh[128][32];
    __shared__ __align__(16) unsigned short sBl[128][32];
    const int tid = threadIdx.x;
    const int eb = blockIdx.x * 128, nb = blockIdx.y * 128, z = blockIdx.z;
    const unsigned short* Bh = (z == 0) ? wqh : (z == 1) ? wkh : wvh;
    const unsigned short* Bl = (z == 0) ? wql : (z == 1) ? wkl : wvl;
    const float* bias = (z == 0) ? bq : (z == 1) ? bk : bv;
    const float scale = (z == 0) ? 0.125f : 1.0f;
    const int w = tid >> 6, lane = tid & 63, lq = lane & 15, quad = lane >> 4;
    const int wr = w >> 1, wc = w & 1;
    const int srow = tid >> 2, sc8 = (tid & 3) * 8;

    // wave-uniform LDS bases (w is wave-uniform)
    unsigned short* dAh0 = &sAh[w*16][0];  unsigned short* dAh1 = &sAh[64 + w*16][0];
    unsigned short* dAl0 = &sAl[w*16][0];  unsigned short* dAl1 = &sAl[64 + w*16][0];
    unsigned short* dBh0 = &sBh[w*16][0];  unsigned short* dBh1 = &sBh[64 + w*16][0];
    unsigned short* dBl0 = &sBl[w*16][0];  unsigned short* dBl1 = &sBl[64 + w*16][0];

    f32x4 acc[4][4];
    #pragma unroll
    for (int i = 0; i < 4; ++i)
        #pragma unroll
        for (int j = 0; j < 4; ++j) acc[i][j] = (f32x4){0,0,0,0};

    for (int k0 = 0; k0 < 1024; k0 += 32) {
        __syncthreads();   // prev-iter frag reads done before overwrite
        gl_lds16(hh + (size_t)(nb + srow) * 1024 + k0 + sc8,      dAh0);
        gl_lds16(hh + (size_t)(nb + srow + 64) * 1024 + k0 + sc8, dAh1);
        gl_lds16(hl + (size_t)(nb + srow) * 1024 + k0 + sc8,      dAl0);
        gl_lds16(hl + (size_t)(nb + srow + 64) * 1024 + k0 + sc8, dAl1);
        gl_lds16(Bh + (size_t)(eb + srow) * 1024 + k0 + sc8,      dBh0);
        gl_lds16(Bh + (size_t)(eb + srow + 64) * 1024 + k0 + sc8, dBh1);
        gl_lds16(Bl + (size_t)(eb + srow) * 1024 + k0 + sc8,      dBl0);
        gl_lds16(Bl + (size_t)(eb + srow + 64) * 1024 + k0 + sc8, dBl1);
        __syncthreads();   // vmcnt(0) drained by compiler -> tile staged

        short8 ah[4], al[4], bhf[4], blf[4];
        #pragma unroll
        for (int t = 0; t < 4; ++t) {
            ah[t]  = *(const short8*)&sAh[wr*64 + t*16 + lq][quad*8];
            al[t]  = *(const short8*)&sAl[wr*64 + t*16 + lq][quad*8];
            bhf[t] = *(const short8*)&sBh[wc*64 + t*16 + lq][quad*8];
            blf[t] = *(const short8*)&sBl[wc*64 + t*16 + lq][quad*8];
        }
        #pragma unroll
        for (int ti = 0; ti < 4; ++ti)
            #pragma unroll
            for (int tj = 0; tj < 4; ++tj) {
                acc[ti][tj] = __builtin_amdgcn_mfma_f32_16x16x32_bf16(ah[ti], bhf[tj], acc[ti][tj], 0, 0, 0);
                acc[ti][tj] = __builtin_amdgcn_mfma_f32_16x16x32_bf16(al[ti], bhf[tj], acc[ti][tj], 0, 0, 0);
                acc[ti][tj] = __builtin_amdgcn_mfma_f32_16x16x32_bf16(ah[ti], blf[tj], acc[ti][tj], 0, 0, 0);
            }
    }

    #pragma unroll
    for (int tj = 0; tj < 4; ++tj) {
        int e = eb + wc*64 + tj*16 + lq;
        float bb = bias[e];
        int h = e >> 6, d = e & 63;
        #pragma unroll
        for (int ti = 0; ti < 4; ++ti) {
            #pragma unroll
            for (int i = 0; i < 4; ++i) {
                int n = nb + wr*64 + ti*16 + quad*4 + i;
                int bidx = n >> 10, t = n & 1023;
                int s = bidx*16 + h;
                float val = (acc[ti][tj][i] + bb) * scale;
                if (z == 2)
                    vt[(((size_t)(s*64 + d)) << 10) + t] = f2b(val);
                else if (z == 0)
                    qb[(((size_t)(s*1024 + t)) << 6) + d] = f2b(val);
                else
                    kb[(((size_t)(s*1024 + t)) << 6) + d] = f2b(val);
            }
        }
    }
}

// ---------------------------------------------------------------------------
// K2: MFMA flash attention (unchanged from R11).
// ---------------------------------------------------------------------------
__global__ __launch_bounds__(256) void k_fused(
    const unsigned short* __restrict__ qb, const unsigned short* __restrict__ kb,
    const unsigned short* __restrict__ vt, const unsigned short* __restrict__ relkB,
    const unsigned short* __restrict__ relvT, const float* __restrict__ relv,
    float* __restrict__ c1, float* __restrict__ c2)
{
    __shared__ __align__(16) unsigned short sP[2][2][16][72];
    __shared__ __align__(16) unsigned short sG[2][16][104];
    __shared__ unsigned short sR[32][273];
    __shared__ float sRed[4][3][32];

    const int tid = threadIdx.x;
    const int m  = blockIdx.y;
    const int q0 = blockIdx.x * 32;
    const int pm = (m & 15) * 4 + (m >> 4);
    const int m2 = (m & 3) * 16 + (m >> 2);
    const int w    = tid >> 6;
    const int lane = tid & 63;
    const int lq   = lane & 15;
    const int quad = lane >> 4;

    #pragma unroll
    for (int sub = 0; sub < 2; ++sub) {
        const unsigned short* qpm = qb + (((size_t)(pm*1024 + q0 + sub*16 + lq)) << 6);
        short8 a0 = *(const short8*)(qpm + quad*8);
        short8 a1 = *(const short8*)(qpm + 32 + quad*8);
        for (int jt = w; jt < 17; jt += 4) {
            const unsigned short* rkb = relkB + (size_t)(jt*16 + lq) * 64;
            short8 b0 = *(const short8*)(rkb + quad*8);
            short8 b1 = *(const short8*)(rkb + 32 + quad*8);
            f32x4 cr = {0,0,0,0};
            cr = __builtin_amdgcn_mfma_f32_16x16x32_bf16(a0, b0, cr, 0, 0, 0);
            cr = __builtin_amdgcn_mfma_f32_16x16x32_bf16(a1, b1, cr, 0, 0, 0);
            #pragma unroll
            for (int i = 0; i < 4; ++i)
                sR[sub*16 + quad*4 + i][jt*16 + lq] = f2b(cr[i]);
        }
    }
    __syncthreads();

    short8 aq0[2], aq1[2];
    #pragma unroll
    for (int sub = 0; sub < 2; ++sub) {
        const unsigned short* qm = qb + (((size_t)(m*1024 + q0 + sub*16 + lq)) << 6);
        aq0[sub] = *(const short8*)(qm + quad*8);
        aq1[sub] = *(const short8*)(qm + 32 + quad*8);
    }
    const float relE0 = relv[w*16 + lq];
    const float relE1 = relv[256*64 + w*16 + lq];

    float lsum[2][4], slow[2][4], shigh[2][4];
    f32x4 c1a[2], c2a[2];
    #pragma unroll
    for (int sub = 0; sub < 2; ++sub) {
        c1a[sub] = (f32x4){0,0,0,0};
        c2a[sub] = (f32x4){0,0,0,0};
        #pragma unroll
        for (int i = 0; i < 4; ++i) {
            lsum[sub][i] = 0.0f; slow[sub][i] = 0.0f; shigh[sub][i] = 0.0f;
        }
    }

    const unsigned short* kbase = kb + (((size_t)(m*1024 + w*16 + lq)) << 6);
    const unsigned short* vbase = vt + (((size_t)(m*64 + w*16 + lq)) << 10);
    short8 ck0 = *(const short8*)(kbase + quad*8);
    short8 ck1 = *(const short8*)(kbase + 32 + quad*8);
    short8 cv0 = *(const short8*)(vbase + quad*8);
    short8 cv1 = *(const short8*)(vbase + 32 + quad*8);

    #pragma unroll 1
    for (int kt = 0; kt < 16; ++kt) {
        const int k0 = kt * 64;
        const int dmin = q0 - k0 - 63;
        const int dmax = q0 + 31 - k0;
        const bool needG = (dmax >= -127) && (dmin <= 127);
        const int buf = kt & 1;

        short8 nk0 = ck0, nk1 = ck1, nv0 = cv0, nv1 = cv1;
        if (kt < 15) {
            const size_t ko = (size_t)(k0 + 64);
            nk0 = *(const short8*)(kbase + (ko << 6) + quad*8);
            nk1 = *(const short8*)(kbase + (ko << 6) + 32 + quad*8);
            nv0 = *(const short8*)(vbase + ko + quad*8);
            nv1 = *(const short8*)(vbase + ko + 32 + quad*8);
        }

        f32x4 s4[2];
        #pragma unroll
        for (int sub = 0; sub < 2; ++sub) {
            s4[sub] = (f32x4){0,0,0,0};
            s4[sub] = __builtin_amdgcn_mfma_f32_16x16x32_bf16(aq0[sub], ck0, s4[sub], 0, 0, 0);
            s4[sub] = __builtin_amdgcn_mfma_f32_16x16x32_bf16(aq1[sub], ck1, s4[sub], 0, 0, 0);
        }

        const int kcol = k0 + w*16 + lq;
        float e[2][4];
        #pragma unroll
        for (int sub = 0; sub < 2; ++sub) {
            #pragma unroll
            for (int i = 0; i < 4; ++i) {
                int row = sub*16 + quad*4 + i;
                int dist = (q0 + row) - kcol;
                int jd = dist < -128 ? 0 : (dist > 128 ? 256 : dist + 128);
                float ev = exp2f((s4[sub][i] + bf16f(sR[row][jd])) * 1.44269504f);
                e[sub][i] = ev;
                lsum[sub][i] += ev;
                if (dist <= -128)     slow[sub][i]  += ev;
                else if (dist >= 128) shigh[sub][i] += ev;
                sP[buf][sub][quad*4 + i][w*16 + lq] = f2b(ev);
            }
        }
        if (needG) {
            #pragma unroll
            for (int i = 0; i < 7; ++i) {
                int idx = tid + i * 256;
                if (idx < 1664) ((unsigned int*)sG)[idx] = 0u;
            }
        }
        __syncthreads();

        if (needG) {
            #pragma unroll
            for (int sub = 0; sub < 2; ++sub) {
                int jminb = q0 + sub*16 - k0 - 63;
                jminb = (jminb < -127 ? -127 : jminb) + 128;
                int jlo8 = jminb & ~7;
                if (jlo8 > 160) jlo8 = 160;
                #pragma unroll
                for (int i = 0; i < 4; ++i) {
                    int row = sub*16 + quad*4 + i;
                    int dist = (q0 + row) - kcol;
                    if (dist > -128 && dist < 128)
                        sG[sub][quad*4 + i][dist + 128 - jlo8] = f2b(e[sub][i]);
                }
            }
        }

        #pragma unroll
        for (int sub = 0; sub < 2; ++sub) {
            short8 ap0 = *(const short8*)&sP[buf][sub][lq][quad*8];
            short8 ap1 = *(const short8*)&sP[buf][sub][lq][32 + quad*8];
            c1a[sub] = __builtin_amdgcn_mfma_f32_16x16x32_bf16(ap0, cv0, c1a[sub], 0, 0, 0);
            c1a[sub] = __builtin_amdgcn_mfma_f32_16x16x32_bf16(ap1, cv1, c1a[sub], 0, 0, 0);
        }

        if (needG) {
            __syncthreads();
            #pragma unroll
            for (int sub = 0; sub < 2; ++sub) {
                int jminb = q0 + sub*16 - k0 - 63;
                jminb = (jminb < -127 ? -127 : jminb) + 128;
                int jlo8 = jminb & ~7;
                if (jlo8 > 160) jlo8 = 160;
                short8 ag0 = *(const short8*)&sG[sub][lq][quad*8];
                short8 ag1 = *(const short8*)&sG[sub][lq][32 + quad*8];
                short8 ag2 = *(const short8*)&sG[sub][lq][64 + quad*8];
                const unsigned short* rrow = relvT + (size_t)(w*16 + lq) * 264 + jlo8;
                short8 br0 = *(const short8*)(rrow + quad*8);
                short8 br1 = *(const short8*)(rrow + 32 + quad*8);
                short8 br2 = *(const short8*)(rrow + 64 + quad*8);
                c2a[sub] = __builtin_amdgcn_mfma_f32_16x16x32_bf16(ag0, br0, c2a[sub], 0, 0, 0);
                c2a[sub] = __builtin_amdgcn_mfma_f32_16x16x32_bf16(ag1, br1, c2a[sub], 0, 0, 0);
                c2a[sub] = __builtin_amdgcn_mfma_f32_16x16x32_bf16(ag2, br2, c2a[sub], 0, 0, 0);
            }
            __syncthreads();
        }

        ck0 = nk0; ck1 = nk1; cv0 = nv0; cv1 = nv1;
    }

    #pragma unroll
    for (int off = 1; off < 16; off <<= 1) {
        #pragma unroll
        for (int sub = 0; sub < 2; ++sub)
            #pragma unroll
            for (int i = 0; i < 4; ++i) {
                lsum[sub][i]  += __shfl_xor(lsum[sub][i],  off, 64);
                slow[sub][i]  += __shfl_xor(slow[sub][i],  off, 64);
                shigh[sub][i] += __shfl_xor(shigh[sub][i], off, 64);
            }
    }
    if (lq == 0) {
        #pragma unroll
        for (int sub = 0; sub < 2; ++sub)
            #pragma unroll
            for (int i = 0; i < 4; ++i) {
                int row = sub*16 + quad*4 + i;
                sRed[w][0][row] = lsum[sub][i];
                sRed[w][1][row] = slow[sub][i];
                sRed[w][2][row] = shigh[sub][i];
            }
    }
    __syncthreads();

    const int b1 = m >> 4,  h1 = m & 15;
    const int b2 = m2 >> 4, h2 = m2 & 15;
    #pragma unroll
    for (int sub = 0; sub < 2; ++sub) {
        #pragma unroll
        for (int i = 0; i < 4; ++i) {
            int row = sub*16 + quad*4 + i;
            float lt = sRed[0][0][row] + sRed[1][0][row] + sRed[2][0][row] + sRed[3][0][row];
            float sl = sRed[0][1][row] + sRed[1][1][row] + sRed[2][1][row] + sRed[3][1][row];
            float sh = sRed[0][2][row] + sRed[1][2][row] + sRed[2][2][row] + sRed[3][2][row];
            float c2v = c2a[sub][i] + sl * relE0 + sh * relE1;
            float inv = 1.0f / lt;
            int col = w*16 + lq;
            c1[(size_t)(b1*1024 + q0 + row) * 1024 + h1*64 + col] = c1a[sub][i] * inv;
            c2[(size_t)(b2*1024 + q0 + row) * 1024 + h2*64 + col] = c2v * inv;
        }
    }
}

// ---------------------------------------------------------------------------
// K3: out = (c1+c2) @ Wo^T + bo via split-bf16 MFMA (exact R11 version).
// ---------------------------------------------------------------------------
__global__ __launch_bounds__(256) void k_gemm_o(
    const float* __restrict__ c1, const float* __restrict__ c2,
    const unsigned short* __restrict__ woh, const unsigned short* __restrict__ wol,
    const float* __restrict__ bo, float* __restrict__ outp)
{
    __shared__ __align__(16) unsigned short sAh[128][48];
    __shared__ __align__(16) unsigned short sAl[128][48];
    __shared__ __align__(16) unsigned short sBh[128][48];
    __shared__ __align__(16) unsigned short sBl[128][48];
    const int tid = threadIdx.x;
    const int eb = blockIdx.x * 128, nb = blockIdx.y * 128;
    const int w = tid >> 6, lane = tid & 63, lq = lane & 15, quad = lane >> 4;
    const int wr = w >> 1, wc = w & 1;
    const int srow = tid >> 2, sc8 = (tid & 3) * 8;

    f32x4 acc[4][4];
    #pragma unroll
    for (int i = 0; i < 4; ++i)
        #pragma unroll
        for (int j = 0; j < 4; ++j) acc[i][j] = (f32x4){0,0,0,0};

    for (int k0 = 0; k0 < 1024; k0 += 32) {
        float av[2][8];
        #pragma unroll
        for (int r2 = 0; r2 < 2; ++r2) {
            size_t off = (size_t)(nb + srow + r2*64) * 1024 + k0 + sc8;
            float4 x0 = *(const float4*)(c1 + off);
            float4 x1 = *(const float4*)(c1 + off + 4);
            float4 y0 = *(const float4*)(c2 + off);
            float4 y1 = *(const float4*)(c2 + off + 4);
            av[r2][0] = x0.x + y0.x; av[r2][1] = x0.y + y0.y;
            av[r2][2] = x0.z + y0.z; av[r2][3] = x0.w + y0.w;
            av[r2][4] = x1.x + y1.x; av[r2][5] = x1.y + y1.y;
            av[r2][6] = x1.z + y1.z; av[r2][7] = x1.w + y1.w;
        }
        uint4 b0h = *(const uint4*)(woh + (size_t)(eb + srow) * 1024 + k0 + sc8);
        uint4 b1h = *(const uint4*)(woh + (size_t)(eb + srow + 64) * 1024 + k0 + sc8);
        uint4 b0l = *(const uint4*)(wol + (size_t)(eb + srow) * 1024 + k0 + sc8);
        uint4 b1l = *(const uint4*)(wol + (size_t)(eb + srow + 64) * 1024 + k0 + sc8);
        __syncthreads();
        #pragma unroll
        for (int r2 = 0; r2 < 2; ++r2) {
            unsigned short hh8[8], ll8[8];
            #pragma unroll
            for (int j = 0; j < 8; ++j) {
                hh8[j] = f2b(av[r2][j]);
                ll8[j] = f2b(av[r2][j] - bf16f(hh8[j]));
            }
            *(uint4*)&sAh[srow + r2*64][sc8] = *(const uint4*)hh8;
            *(uint4*)&sAl[srow + r2*64][sc8] = *(const uint4*)ll8;
        }
        *(uint4*)&sBh[srow][sc8] = b0h;  *(uint4*)&sBh[srow + 64][sc8] = b1h;
        *(uint4*)&sBl[srow][sc8] = b0l;  *(uint4*)&sBl[srow + 64][sc8] = b1l;
        __syncthreads();

        short8 ah[4], al[4], bhf[4], blf[4];
        #pragma unroll
        for (int t = 0; t < 4; ++t) {
            ah[t]  = *(const short8*)&sAh[wr*64 + t*16 + lq][quad*8];
            al[t]  = *(const short8*)&sAl[wr*64 + t*16 + lq][quad*8];
            bhf[t] = *(const short8*)&sBh[wc*64 + t*16 + lq][quad*8];
            blf[t] = *(const short8*)&sBl[wc*64 + t*16 + lq][quad*8];
        }
        #pragma unroll
        for (int ti = 0; ti < 4; ++ti)
            #pragma unroll
            for (int tj = 0; tj < 4; ++tj) {
                acc[ti][tj] = __builtin_amdgcn_mfma_f32_16x16x32_bf16(ah[ti], bhf[tj], acc[ti][tj], 0, 0, 0);
                acc[ti][tj] = __builtin_amdgcn_mfma_f32_16x16x32_bf16(al[ti], bhf[tj], acc[ti][tj], 0, 0, 0);
                acc[ti][tj] = __builtin_amdgcn_mfma_f32_16x16x32_bf16(ah[ti], blf[tj], acc[ti][tj], 0, 0, 0);
            }
    }

    #pragma unroll
    for (int tj = 0; tj < 4; ++tj) {
        int e = eb + wc*64 + tj*16 + lq;
        float bb = bo[e];
        #pragma unroll
        for (int ti = 0; ti < 4; ++ti) {
            #pragma unroll
            for (int i = 0; i < 4; ++i) {
                int n = nb + wr*64 + ti*16 + quad*4 + i;
                outp[(size_t)n * 1024 + e] = acc[ti][tj][i] + bb;
            }
        }
    }
}

// ---------------------------------------------------------------------------
extern "C" void kernel_launch(void* const* d_in, const int* in_sizes, int n_in,
                              void* d_out, int out_size, void* d_ws, size_t ws_size,
                              hipStream_t stream) {
    const float* hs   = (const float*)d_in[0];
    const float* Wq   = (const float*)d_in[1];
    const float* bq   = (const float*)d_in[2];
    const float* Wk   = (const float*)d_in[3];
    const float* bk   = (const float*)d_in[4];
    const float* Wv   = (const float*)d_in[5];
    const float* bv   = (const float*)d_in[6];
    const float* Wo   = (const float*)d_in[7];
    const float* bo   = (const float*)d_in[8];
    const float* relk = (const float*)d_in[9];
    const float* relv = (const float*)d_in[10];
    float* out = (float*)d_out;

    unsigned short* wsu = (unsigned short*)d_ws;
    unsigned short* qbp   = wsu;
    unsigned short* kbp   = wsu + 4194304;
    unsigned short* vtp   = wsu + 8388608;
    unsigned short* relkB = wsu + 12582912;
    unsigned short* relvT = wsu + 12600320;
    float* c1 = (float*)(wsu + 12617360);
    float* c2 = c1 + 4194304;
    unsigned short* hh  = wsu + 29394576;
    unsigned short* hl  = hh + 4194304;
    unsigned short* wqh = hl + 4194304;
    unsigned short* wql = wqh + 1048576;
    unsigned short* wkh = wql + 1048576;
    unsigned short* wkl = wkh + 1048576;
    unsigned short* wvh = wkl + 1048576;
    unsigned short* wvl = wvh + 1048576;
    unsigned short* woh = wvl + 1048576;
    unsigned short* wol = woh + 1048576;

    k_prep<<<dim3(512, 6), 256, 0, stream>>>(hs, Wq, Wk, Wv, Wo, relk, relv,
                                             hh, hl, wqh, wql, wkh, wkl,
                                             wvh, wvl, woh, wol, relkB, relvT);
    k_gemm_qkv<<<dim3(8, 32, 3), 256, 0, stream>>>(hh, hl, wqh, wql, wkh, wkl,
                                                   wvh, wvl, bq, bk, bv,
                                                   qbp, kbp, vtp);
    k_fused<<<dim3(32, 64), 256, 0, stream>>>(qbp, kbp, vtp, relkB, relvT, relv, c1, c2);
    k_gemm_o<<<dim3(8, 32), 256, 0, stream>>>(c1, c2, woh, wol, bo, out);
}

// Round 14
// 437.348 us; speedup vs baseline: 2.1486x; 1.0134x over previous
//
#include <hip/hip_runtime.h>
#include <hip/hip_bf16.h>

// B=4, T=1024, E=1024, H=16, D=64, P=257.  Slot s = b*16+h (64 slots).
// Quirk: score slot m uses rel-K of slot pm=(m&15)*4+(m>>4); attn of slot m
// feeds w2 output of slot m2=(m&3)*16+(m>>2).
// R14: GEMMs retiled 128x64 (qkv grid 1536 = ~5 blocks/CU vs 3; o grid 512)
// + 16B-granule swizzle (granule (row,c) stored at col (c+(row>>1))&3):
// frag reads spread all 8 bank-groups per 32-lane phase (R11/R13 had 6.29M
// conflicts from quads hitting half the groups).  With global_load_lds the
// swizzle permutes the per-lane GLOBAL column; LDS pattern stays lane*16.

typedef __attribute__((ext_vector_type(8))) short short8;
typedef __attribute__((ext_vector_type(4))) float f32x4;

__device__ __forceinline__ float bf16f(unsigned int u) {
    union { unsigned int i; float f; } v; v.i = u << 16; return v.f;
}
__device__ __forceinline__ unsigned short f2b(float x) {
    __hip_bfloat16 h = __float2bfloat16(x);
    return *reinterpret_cast<unsigned short*>(&h);
}
__device__ __forceinline__ void gl_lds16(const unsigned short* g, unsigned short* l) {
    __builtin_amdgcn_global_load_lds(
        (const __attribute__((address_space(1))) void*)g,
        (__attribute__((address_space(3))) void*)l, 16, 0, 0);
}

// ---------------------------------------------------------------------------
// K0: prep.  z=0..4: split fp32 -> (hi,lo) bf16.  z=5: rel tables.
// ---------------------------------------------------------------------------
__global__ __launch_bounds__(256) void k_prep(
    const float* __restrict__ hs, const float* __restrict__ Wq,
    const float* __restrict__ Wk, const float* __restrict__ Wv,
    const float* __restrict__ Wo, const float* __restrict__ relk,
    const float* __restrict__ relv,
    unsigned short* __restrict__ hh, unsigned short* __restrict__ hl,
    unsigned short* __restrict__ wqh, unsigned short* __restrict__ wql,
    unsigned short* __restrict__ wkh, unsigned short* __restrict__ wkl,
    unsigned short* __restrict__ wvh, unsigned short* __restrict__ wvl,
    unsigned short* __restrict__ woh, unsigned short* __restrict__ wol,
    unsigned short* __restrict__ relkB, unsigned short* __restrict__ relvT)
{
    const int z = blockIdx.y;
    const int tid = threadIdx.x;
    if (z < 5) {
        const float* src = (z == 0) ? hs : (z == 1) ? Wq : (z == 2) ? Wk
                         : (z == 3) ? Wv : Wo;
        unsigned short* hi = (z == 0) ? hh : (z == 1) ? wqh : (z == 2) ? wkh
                           : (z == 3) ? wvh : woh;
        unsigned short* lo = (z == 0) ? hl : (z == 1) ? wql : (z == 2) ? wkl
                           : (z == 3) ? wvl : wol;
        const int n4 = (z == 0) ? 1048576 : 262144;
        const int stride = gridDim.x * 256;
        for (int i = blockIdx.x * 256 + tid; i < n4; i += stride) {
            float4 x = *(const float4*)(src + i*4);
            unsigned short h[4], l[4];
            float xs[4] = {x.x, x.y, x.z, x.w};
            #pragma unroll
            for (int j = 0; j < 4; ++j) {
                h[j] = f2b(xs[j]);
                l[j] = f2b(xs[j] - bf16f(h[j]));
            }
            *(ushort4*)(hi + i*4) = make_ushort4(h[0], h[1], h[2], h[3]);
            *(ushort4*)(lo + i*4) = make_ushort4(l[0], l[1], l[2], l[3]);
        }
    } else if (blockIdx.x == 0) {
        for (int i = tid; i < 272*64; i += 256) {
            int j = i >> 6;
            relkB[i] = (j < 257) ? f2b(relk[i]) : (unsigned short)0;
        }
        int d = tid >> 2, grp = tid & 3;
        for (int jj = 0; jj < 66; ++jj) {
            int j = grp*66 + jj;
            if (j < 264)
                relvT[d*264 + j] = (j < 257) ? f2b(relv[j*64 + d]) : (unsigned short)0;
        }
    }
}

// ---------------------------------------------------------------------------
// K1: QKV projection, 128x64 tile, async global_load_lds + granule swizzle.
// Grid (16, 32, 3) = 1536 blocks.  Waves 2x2: wr n-half(64), wc e-half(32).
// ---------------------------------------------------------------------------
__global__ __launch_bounds__(256) void k_gemm_qkv(
    const unsigned short* __restrict__ hh, const unsigned short* __restrict__ hl,
    const unsigned short* __restrict__ wqh, const unsigned short* __restrict__ wql,
    const unsigned short* __restrict__ wkh, const unsigned short* __restrict__ wkl,
    const unsigned short* __restrict__ wvh, const unsigned short* __restrict__ wvl,
    const float* __restrict__ bq, const float* __restrict__ bk,
    const float* __restrict__ bv,
    unsigned short* __restrict__ qb, unsigned short* __restrict__ kb,
    unsigned short* __restrict__ vt)
{
    __shared__ __align__(16) unsigned short sAh[128][32];
    __shared__ __align__(16) unsigned short sAl[128][32];
    __shared__ __align__(16) unsigned short sBh[64][32];
    __shared__ __align__(16) unsigned short sBl[64][32];
    const int tid = threadIdx.x;
    const int eb = blockIdx.x * 64, nb = blockIdx.y * 128, z = blockIdx.z;
    const unsigned short* Bh = (z == 0) ? wqh : (z == 1) ? wkh : wvh;
    const unsigned short* Bl = (z == 0) ? wql : (z == 1) ? wkl : wvl;
    const float* bias = (z == 0) ? bq : (z == 1) ? bk : bv;
    const float scale = (z == 0) ? 0.125f : 1.0f;
    const int w = tid >> 6, lane = tid & 63, lq = lane & 15, quad = lane >> 4;
    const int wr = w >> 1, wc = w & 1;

    // staging: lane l -> LDS slot (w*16 + l/4, l%4); fetch global granule
    // col pc so that logical col c lands at physical (c+(row>>1))&3.
    const int prow = lane >> 2;
    const int pc8  = ((((lane & 3) - ((lane >> 3) & 3)) & 3)) * 8;
    unsigned short* dAh0 = &sAh[w*16][0];  unsigned short* dAh1 = &sAh[64 + w*16][0];
    unsigned short* dAl0 = &sAl[w*16][0];  unsigned short* dAl1 = &sAl[64 + w*16][0];
    unsigned short* dBh0 = &sBh[w*16][0];  unsigned short* dBl0 = &sBl[w*16][0];
    const int arow = nb + w*16 + prow;
    const int brow = eb + w*16 + prow;

    f32x4 acc[4][2];
    #pragma unroll
    for (int i = 0; i < 4; ++i)
        #pragma unroll
        for (int j = 0; j < 2; ++j) acc[i][j] = (f32x4){0,0,0,0};

    const int pcol = ((quad + (lq >> 1)) & 3) * 8;   // swizzled frag column

    for (int k0 = 0; k0 < 1024; k0 += 32) {
        __syncthreads();   // prev-iter frag reads done before overwrite
        gl_lds16(hh + (size_t)arow * 1024 + k0 + pc8,        dAh0);
        gl_lds16(hh + (size_t)(arow + 64) * 1024 + k0 + pc8, dAh1);
        gl_lds16(hl + (size_t)arow * 1024 + k0 + pc8,        dAl0);
        gl_lds16(hl + (size_t)(arow + 64) * 1024 + k0 + pc8, dAl1);
        gl_lds16(Bh + (size_t)brow * 1024 + k0 + pc8,        dBh0);
        gl_lds16(Bl + (size_t)brow * 1024 + k0 + pc8,        dBl0);
        __syncthreads();   // vmcnt drained -> tile staged

        short8 ah[4], al[4], bhf[2], blf[2];
        #pragma unroll
        for (int t = 0; t < 4; ++t) {
            ah[t] = *(const short8*)&sAh[wr*64 + t*16 + lq][pcol];
            al[t] = *(const short8*)&sAl[wr*64 + t*16 + lq][pcol];
        }
        #pragma unroll
        for (int t = 0; t < 2; ++t) {
            bhf[t] = *(const short8*)&sBh[wc*32 + t*16 + lq][pcol];
            blf[t] = *(const short8*)&sBl[wc*32 + t*16 + lq][pcol];
        }
        #pragma unroll
        for (int ti = 0; ti < 4; ++ti)
            #pragma unroll
            for (int tj = 0; tj < 2; ++tj) {
                acc[ti][tj] = __builtin_amdgcn_mfma_f32_16x16x32_bf16(ah[ti], bhf[tj], acc[ti][tj], 0, 0, 0);
                acc[ti][tj] = __builtin_amdgcn_mfma_f32_16x16x32_bf16(al[ti], bhf[tj], acc[ti][tj], 0, 0, 0);
                acc[ti][tj] = __builtin_amdgcn_mfma_f32_16x16x32_bf16(ah[ti], blf[tj], acc[ti][tj], 0, 0, 0);
            }
    }

    #pragma unroll
    for (int tj = 0; tj < 2; ++tj) {
        int e = eb + wc*32 + tj*16 + lq;
        float bb = bias[e];
        int h = e >> 6, d = e & 63;
        #pragma unroll
        for (int ti = 0; ti < 4; ++ti) {
            #pragma unroll
            for (int i = 0; i < 4; ++i) {
                int n = nb + wr*64 + ti*16 + quad*4 + i;
                int bidx = n >> 10, t = n & 1023;
                int s = bidx*16 + h;
                float val = (acc[ti][tj][i] + bb) * scale;
                if (z == 2)
                    vt[(((size_t)(s*64 + d)) << 10) + t] = f2b(val);
                else if (z == 0)
                    qb[(((size_t)(s*1024 + t)) << 6) + d] = f2b(val);
                else
                    kb[(((size_t)(s*1024 + t)) << 6) + d] = f2b(val);
            }
        }
    }
}

// ---------------------------------------------------------------------------
// K2: MFMA flash attention (unchanged from R11/R13).
// ---------------------------------------------------------------------------
__global__ __launch_bounds__(256) void k_fused(
    const unsigned short* __restrict__ qb, const unsigned short* __restrict__ kb,
    const unsigned short* __restrict__ vt, const unsigned short* __restrict__ relkB,
    const unsigned short* __restrict__ relvT, const float* __restrict__ relv,
    float* __restrict__ c1, float* __restrict__ c2)
{
    __shared__ __align__(16) unsigned short sP[2][2][16][72];
    __shared__ __align__(16) unsigned short sG[2][16][104];
    __shared__ unsigned short sR[32][273];
    __shared__ float sRed[4][3][32];

    const int tid = threadIdx.x;
    const int m  = blockIdx.y;
    const int q0 = blockIdx.x * 32;
    const int pm = (m & 15) * 4 + (m >> 4);
    const int m2 = (m & 3) * 16 + (m >> 2);
    const int w    = tid >> 6;
    const int lane = tid & 63;
    const int lq   = lane & 15;
    const int quad = lane >> 4;

    #pragma unroll
    for (int sub = 0; sub < 2; ++sub) {
        const unsigned short* qpm = qb + (((size_t)(pm*1024 + q0 + sub*16 + lq)) << 6);
        short8 a0 = *(const short8*)(qpm + quad*8);
        short8 a1 = *(const short8*)(qpm + 32 + quad*8);
        for (int jt = w; jt < 17; jt += 4) {
            const unsigned short* rkb = relkB + (size_t)(jt*16 + lq) * 64;
            short8 b0 = *(const short8*)(rkb + quad*8);
            short8 b1 = *(const short8*)(rkb + 32 + quad*8);
            f32x4 cr = {0,0,0,0};
            cr = __builtin_amdgcn_mfma_f32_16x16x32_bf16(a0, b0, cr, 0, 0, 0);
            cr = __builtin_amdgcn_mfma_f32_16x16x32_bf16(a1, b1, cr, 0, 0, 0);
            #pragma unroll
            for (int i = 0; i < 4; ++i)
                sR[sub*16 + quad*4 + i][jt*16 + lq] = f2b(cr[i]);
        }
    }
    __syncthreads();

    short8 aq0[2], aq1[2];
    #pragma unroll
    for (int sub = 0; sub < 2; ++sub) {
        const unsigned short* qm = qb + (((size_t)(m*1024 + q0 + sub*16 + lq)) << 6);
        aq0[sub] = *(const short8*)(qm + quad*8);
        aq1[sub] = *(const short8*)(qm + 32 + quad*8);
    }
    const float relE0 = relv[w*16 + lq];
    const float relE1 = relv[256*64 + w*16 + lq];

    float lsum[2][4], slow[2][4], shigh[2][4];
    f32x4 c1a[2], c2a[2];
    #pragma unroll
    for (int sub = 0; sub < 2; ++sub) {
        c1a[sub] = (f32x4){0,0,0,0};
        c2a[sub] = (f32x4){0,0,0,0};
        #pragma unroll
        for (int i = 0; i < 4; ++i) {
            lsum[sub][i] = 0.0f; slow[sub][i] = 0.0f; shigh[sub][i] = 0.0f;
        }
    }

    const unsigned short* kbase = kb + (((size_t)(m*1024 + w*16 + lq)) << 6);
    const unsigned short* vbase = vt + (((size_t)(m*64 + w*16 + lq)) << 10);
    short8 ck0 = *(const short8*)(kbase + quad*8);
    short8 ck1 = *(const short8*)(kbase + 32 + quad*8);
    short8 cv0 = *(const short8*)(vbase + quad*8);
    short8 cv1 = *(const short8*)(vbase + 32 + quad*8);

    #pragma unroll 1
    for (int kt = 0; kt < 16; ++kt) {
        const int k0 = kt * 64;
        const int dmin = q0 - k0 - 63;
        const int dmax = q0 + 31 - k0;
        const bool needG = (dmax >= -127) && (dmin <= 127);
        const int buf = kt & 1;

        short8 nk0 = ck0, nk1 = ck1, nv0 = cv0, nv1 = cv1;
        if (kt < 15) {
            const size_t ko = (size_t)(k0 + 64);
            nk0 = *(const short8*)(kbase + (ko << 6) + quad*8);
            nk1 = *(const short8*)(kbase + (ko << 6) + 32 + quad*8);
            nv0 = *(const short8*)(vbase + ko + quad*8);
            nv1 = *(const short8*)(vbase + ko + 32 + quad*8);
        }

        f32x4 s4[2];
        #pragma unroll
        for (int sub = 0; sub < 2; ++sub) {
            s4[sub] = (f32x4){0,0,0,0};
            s4[sub] = __builtin_amdgcn_mfma_f32_16x16x32_bf16(aq0[sub], ck0, s4[sub], 0, 0, 0);
            s4[sub] = __builtin_amdgcn_mfma_f32_16x16x32_bf16(aq1[sub], ck1, s4[sub], 0, 0, 0);
        }

        const int kcol = k0 + w*16 + lq;
        float e[2][4];
        #pragma unroll
        for (int sub = 0; sub < 2; ++sub) {
            #pragma unroll
            for (int i = 0; i < 4; ++i) {
                int row = sub*16 + quad*4 + i;
                int dist = (q0 + row) - kcol;
                int jd = dist < -128 ? 0 : (dist > 128 ? 256 : dist + 128);
                float ev = exp2f((s4[sub][i] + bf16f(sR[row][jd])) * 1.44269504f);
                e[sub][i] = ev;
                lsum[sub][i] += ev;
                if (dist <= -128)     slow[sub][i]  += ev;
                else if (dist >= 128) shigh[sub][i] += ev;
                sP[buf][sub][quad*4 + i][w*16 + lq] = f2b(ev);
            }
        }
        if (needG) {
            #pragma unroll
            for (int i = 0; i < 7; ++i) {
                int idx = tid + i * 256;
                if (idx < 1664) ((unsigned int*)sG)[idx] = 0u;
            }
        }
        __syncthreads();

        if (needG) {
            #pragma unroll
            for (int sub = 0; sub < 2; ++sub) {
                int jminb = q0 + sub*16 - k0 - 63;
                jminb = (jminb < -127 ? -127 : jminb) + 128;
                int jlo8 = jminb & ~7;
                if (jlo8 > 160) jlo8 = 160;
                #pragma unroll
                for (int i = 0; i < 4; ++i) {
                    int row = sub*16 + quad*4 + i;
                    int dist = (q0 + row) - kcol;
                    if (dist > -128 && dist < 128)
                        sG[sub][quad*4 + i][dist + 128 - jlo8] = f2b(e[sub][i]);
                }
            }
        }

        #pragma unroll
        for (int sub = 0; sub < 2; ++sub) {
            short8 ap0 = *(const short8*)&sP[buf][sub][lq][quad*8];
            short8 ap1 = *(const short8*)&sP[buf][sub][lq][32 + quad*8];
            c1a[sub] = __builtin_amdgcn_mfma_f32_16x16x32_bf16(ap0, cv0, c1a[sub], 0, 0, 0);
            c1a[sub] = __builtin_amdgcn_mfma_f32_16x16x32_bf16(ap1, cv1, c1a[sub], 0, 0, 0);
        }

        if (needG) {
            __syncthreads();
            #pragma unroll
            for (int sub = 0; sub < 2; ++sub) {
                int jminb = q0 + sub*16 - k0 - 63;
                jminb = (jminb < -127 ? -127 : jminb) + 128;
                int jlo8 = jminb & ~7;
                if (jlo8 > 160) jlo8 = 160;
                short8 ag0 = *(const short8*)&sG[sub][lq][quad*8];
                short8 ag1 = *(const short8*)&sG[sub][lq][32 + quad*8];
                short8 ag2 = *(const short8*)&sG[sub][lq][64 + quad*8];
                const unsigned short* rrow = relvT + (size_t)(w*16 + lq) * 264 + jlo8;
                short8 br0 = *(const short8*)(rrow + quad*8);
                short8 br1 = *(const short8*)(rrow + 32 + quad*8);
                short8 br2 = *(const short8*)(rrow + 64 + quad*8);
                c2a[sub] = __builtin_amdgcn_mfma_f32_16x16x32_bf16(ag0, br0, c2a[sub], 0, 0, 0);
                c2a[sub] = __builtin_amdgcn_mfma_f32_16x16x32_bf16(ag1, br1, c2a[sub], 0, 0, 0);
                c2a[sub] = __builtin_amdgcn_mfma_f32_16x16x32_bf16(ag2, br2, c2a[sub], 0, 0, 0);
            }
            __syncthreads();
        }

        ck0 = nk0; ck1 = nk1; cv0 = nv0; cv1 = nv1;
    }

    #pragma unroll
    for (int off = 1; off < 16; off <<= 1) {
        #pragma unroll
        for (int sub = 0; sub < 2; ++sub)
            #pragma unroll
            for (int i = 0; i < 4; ++i) {
                lsum[sub][i]  += __shfl_xor(lsum[sub][i],  off, 64);
                slow[sub][i]  += __shfl_xor(slow[sub][i],  off, 64);
                shigh[sub][i] += __shfl_xor(shigh[sub][i], off, 64);
            }
    }
    if (lq == 0) {
        #pragma unroll
        for (int sub = 0; sub < 2; ++sub)
            #pragma unroll
            for (int i = 0; i < 4; ++i) {
                int row = sub*16 + quad*4 + i;
                sRed[w][0][row] = lsum[sub][i];
                sRed[w][1][row] = slow[sub][i];
                sRed[w][2][row] = shigh[sub][i];
            }
    }
    __syncthreads();

    const int b1 = m >> 4,  h1 = m & 15;
    const int b2 = m2 >> 4, h2 = m2 & 15;
    #pragma unroll
    for (int sub = 0; sub < 2; ++sub) {
        #pragma unroll
        for (int i = 0; i < 4; ++i) {
            int row = sub*16 + quad*4 + i;
            float lt = sRed[0][0][row] + sRed[1][0][row] + sRed[2][0][row] + sRed[3][0][row];
            float sl = sRed[0][1][row] + sRed[1][1][row] + sRed[2][1][row] + sRed[3][1][row];
            float sh = sRed[0][2][row] + sRed[1][2][row] + sRed[2][2][row] + sRed[3][2][row];
            float c2v = c2a[sub][i] + sl * relE0 + sh * relE1;
            float inv = 1.0f / lt;
            int col = w*16 + lq;
            c1[(size_t)(b1*1024 + q0 + row) * 1024 + h1*64 + col] = c1a[sub][i] * inv;
            c2[(size_t)(b2*1024 + q0 + row) * 1024 + h2*64 + col] = c2v * inv;
        }
    }
}

// ---------------------------------------------------------------------------
// K3: out = (c1+c2) @ Wo^T + bo, 128x64 tile, swizzled LDS; A split on the
// fly (sync staging), B via global_load_lds.  Grid (16, 32) = 512 blocks.
// ---------------------------------------------------------------------------
__global__ __launch_bounds__(256) void k_gemm_o(
    const float* __restrict__ c1, const float* __restrict__ c2,
    const unsigned short* __restrict__ woh, const unsigned short* __restrict__ wol,
    const float* __restrict__ bo, float* __restrict__ outp)
{
    __shared__ __align__(16) unsigned short sAh[128][32];
    __shared__ __align__(16) unsigned short sAl[128][32];
    __shared__ __align__(16) unsigned short sBh[64][32];
    __shared__ __align__(16) unsigned short sBl[64][32];
    const int tid = threadIdx.x;
    const int eb = blockIdx.x * 64, nb = blockIdx.y * 128;
    const int w = tid >> 6, lane = tid & 63, lq = lane & 15, quad = lane >> 4;
    const int wr = w >> 1, wc = w & 1;

    // A staging (sync): thread -> granules (ar0, ac) and (ar0+64, ac)
    const int ar0 = tid >> 2, ac = tid & 3;
    const int swc = (((tid & 3) + ((tid >> 3) & 3)) & 3) * 8;  // swizzled col
    // B staging (async): lane slot (w*16 + lane/4, lane%4), permuted global col
    const int prow = lane >> 2;
    const int pc8  = ((((lane & 3) - ((lane >> 3) & 3)) & 3)) * 8;
    unsigned short* dBh0 = &sBh[w*16][0];
    unsigned short* dBl0 = &sBl[w*16][0];
    const int brow = eb + w*16 + prow;

    f32x4 acc[4][2];
    #pragma unroll
    for (int i = 0; i < 4; ++i)
        #pragma unroll
        for (int j = 0; j < 2; ++j) acc[i][j] = (f32x4){0,0,0,0};

    const int pcol = ((quad + (lq >> 1)) & 3) * 8;

    for (int k0 = 0; k0 < 1024; k0 += 32) {
        size_t o0 = (size_t)(nb + ar0) * 1024 + k0 + ac*8;
        size_t o1 = (size_t)(nb + ar0 + 64) * 1024 + k0 + ac*8;
        float4 x0 = *(const float4*)(c1 + o0), x1 = *(const float4*)(c1 + o0 + 4);
        float4 y0 = *(const float4*)(c2 + o0), y1 = *(const float4*)(c2 + o0 + 4);
        float4 X0 = *(const float4*)(c1 + o1), X1 = *(const float4*)(c1 + o1 + 4);
        float4 Y0 = *(const float4*)(c2 + o1), Y1 = *(const float4*)(c2 + o1 + 4);
        __syncthreads();   // prev-iter frag reads done
        gl_lds16(woh + (size_t)brow * 1024 + k0 + pc8, dBh0);
        gl_lds16(wol + (size_t)brow * 1024 + k0 + pc8, dBl0);
        {
            float a0[8] = {x0.x+y0.x, x0.y+y0.y, x0.z+y0.z, x0.w+y0.w,
                           x1.x+y1.x, x1.y+y1.y, x1.z+y1.z, x1.w+y1.w};
            float a1[8] = {X0.x+Y0.x, X0.y+Y0.y, X0.z+Y0.z, X0.w+Y0.w,
                           X1.x+Y1.x, X1.y+Y1.y, X1.z+Y1.z, X1.w+Y1.w};
            unsigned short h8[8], l8[8], H8[8], L8[8];
            #pragma unroll
            for (int j = 0; j < 8; ++j) {
                h8[j] = f2b(a0[j]);  l8[j] = f2b(a0[j] - bf16f(h8[j]));
                H8[j] = f2b(a1[j]);  L8[j] = f2b(a1[j] - bf16f(H8[j]));
            }
            *(uint4*)&sAh[ar0][swc]      = *(const uint4*)h8;
            *(uint4*)&sAl[ar0][swc]      = *(const uint4*)l8;
            *(uint4*)&sAh[ar0 + 64][swc] = *(const uint4*)H8;
            *(uint4*)&sAl[ar0 + 64][swc] = *(const uint4*)L8;
        }
        __syncthreads();   // A writes + B async staged

        short8 ah[4], al[4], bhf[2], blf[2];
        #pragma unroll
        for (int t = 0; t < 4; ++t) {
            ah[t] = *(const short8*)&sAh[wr*64 + t*16 + lq][pcol];
            al[t] = *(const short8*)&sAl[wr*64 + t*16 + lq][pcol];
        }
        #pragma unroll
        for (int t = 0; t < 2; ++t) {
            bhf[t] = *(const short8*)&sBh[wc*32 + t*16 + lq][pcol];
            blf[t] = *(const short8*)&sBl[wc*32 + t*16 + lq][pcol];
        }
        #pragma unroll
        for (int ti = 0; ti < 4; ++ti)
            #pragma unroll
            for (int tj = 0; tj < 2; ++tj) {
                acc[ti][tj] = __builtin_amdgcn_mfma_f32_16x16x32_bf16(ah[ti], bhf[tj], acc[ti][tj], 0, 0, 0);
                acc[ti][tj] = __builtin_amdgcn_mfma_f32_16x16x32_bf16(al[ti], bhf[tj], acc[ti][tj], 0, 0, 0);
                acc[ti][tj] = __builtin_amdgcn_mfma_f32_16x16x32_bf16(ah[ti], blf[tj], acc[ti][tj], 0, 0, 0);
            }
    }

    #pragma unroll
    for (int tj = 0; tj < 2; ++tj) {
        int e = eb + wc*32 + tj*16 + lq;
        float bb = bo[e];
        #pragma unroll
        for (int ti = 0; ti < 4; ++ti) {
            #pragma unroll
            for (int i = 0; i < 4; ++i) {
                int n = nb + wr*64 + ti*16 + quad*4 + i;
                outp[(size_t)n * 1024 + e] = acc[ti][tj][i] + bb;
            }
        }
    }
}

// ---------------------------------------------------------------------------
extern "C" void kernel_launch(void* const* d_in, const int* in_sizes, int n_in,
                              void* d_out, int out_size, void* d_ws, size_t ws_size,
                              hipStream_t stream) {
    const float* hs   = (const float*)d_in[0];
    const float* Wq   = (const float*)d_in[1];
    const float* bq   = (const float*)d_in[2];
    const float* Wk   = (const float*)d_in[3];
    const float* bk   = (const float*)d_in[4];
    const float* Wv   = (const float*)d_in[5];
    const float* bv   = (const float*)d_in[6];
    const float* Wo   = (const float*)d_in[7];
    const float* bo   = (const float*)d_in[8];
    const float* relk = (const float*)d_in[9];
    const float* relv = (const float*)d_in[10];
    float* out = (float*)d_out;

    unsigned short* wsu = (unsigned short*)d_ws;
    unsigned short* qbp   = wsu;
    unsigned short* kbp   = wsu + 4194304;
    unsigned short* vtp   = wsu + 8388608;
    unsigned short* relkB = wsu + 12582912;
    unsigned short* relvT = wsu + 12600320;
    float* c1 = (float*)(wsu + 12617360);
    float* c2 = c1 + 4194304;
    unsigned short* hh  = wsu + 29394576;
    unsigned short* hl  = hh + 4194304;
    unsigned short* wqh = hl + 4194304;
    unsigned short* wql = wqh + 1048576;
    unsigned short* wkh = wql + 1048576;
    unsigned short* wkl = wkh + 1048576;
    unsigned short* wvh = wkl + 1048576;
    unsigned short* wvl = wvh + 1048576;
    unsigned short* woh = wvl + 1048576;
    unsigned short* wol = woh + 1048576;

    k_prep<<<dim3(512, 6), 256, 0, stream>>>(hs, Wq, Wk, Wv, Wo, relk, relv,
                                             hh, hl, wqh, wql, wkh, wkl,
                                             wvh, wvl, woh, wol, relkB, relvT);
    k_gemm_qkv<<<dim3(16, 32, 3), 256, 0, stream>>>(hh, hl, wqh, wql, wkh, wkl,
                                                    wvh, wvl, bq, bk, bv,
                                                    qbp, kbp, vtp);
    k_fused<<<dim3(32, 64), 256, 0, stream>>>(qbp, kbp, vtp, relkB, relvT, relv, c1, c2);
    k_gemm_o<<<dim3(16, 32), 256, 0, stream>>>(c1, c2, woh, wol, bo, out);
}

// Round 15
// 425.782 us; speedup vs baseline: 2.2069x; 1.0272x over previous
//
#include <hip/hip_runtime.h>
#include <hip/hip_bf16.h>

// B=4, T=1024, E=1024, H=16, D=64, P=257.  Slot s = b*16+h (64 slots).
// Quirk: score slot m uses rel-K of slot pm=(m&15)*4+(m>>4); attn of slot m
// feeds w2 output of slot m2=(m&3)*16+(m>>2).
// R15: k_gemm_qkv gets (a) LDS double-buffer w/ cross-iteration async
// global_load_lds (tile k+1 issued right after the barrier publishing k ->
// next barrier's vmcnt(0) drain is ~free), (b) 2-MFMA split (AhBh+AlBh; the
// dropped A*Bl term is below the bf16 output-rounding of qb/kb/vt).
// k_gemm_o keeps full 3-MFMA (fp32 output margin).  R14: conflicts=0 kept.

typedef __attribute__((ext_vector_type(8))) short short8;
typedef __attribute__((ext_vector_type(4))) float f32x4;

__device__ __forceinline__ float bf16f(unsigned int u) {
    union { unsigned int i; float f; } v; v.i = u << 16; return v.f;
}
__device__ __forceinline__ unsigned short f2b(float x) {
    __hip_bfloat16 h = __float2bfloat16(x);
    return *reinterpret_cast<unsigned short*>(&h);
}
__device__ __forceinline__ void gl_lds16(const unsigned short* g, unsigned short* l) {
    __builtin_amdgcn_global_load_lds(
        (const __attribute__((address_space(1))) void*)g,
        (__attribute__((address_space(3))) void*)l, 16, 0, 0);
}

// ---------------------------------------------------------------------------
// K0: prep.  z=0..4: split fp32 -> (hi,lo) bf16.  z=5: rel tables.
// ---------------------------------------------------------------------------
__global__ __launch_bounds__(256) void k_prep(
    const float* __restrict__ hs, const float* __restrict__ Wq,
    const float* __restrict__ Wk, const float* __restrict__ Wv,
    const float* __restrict__ Wo, const float* __restrict__ relk,
    const float* __restrict__ relv,
    unsigned short* __restrict__ hh, unsigned short* __restrict__ hl,
    unsigned short* __restrict__ wqh, unsigned short* __restrict__ wql,
    unsigned short* __restrict__ wkh, unsigned short* __restrict__ wkl,
    unsigned short* __restrict__ wvh, unsigned short* __restrict__ wvl,
    unsigned short* __restrict__ woh, unsigned short* __restrict__ wol,
    unsigned short* __restrict__ relkB, unsigned short* __restrict__ relvT)
{
    const int z = blockIdx.y;
    const int tid = threadIdx.x;
    if (z < 5) {
        const float* src = (z == 0) ? hs : (z == 1) ? Wq : (z == 2) ? Wk
                         : (z == 3) ? Wv : Wo;
        unsigned short* hi = (z == 0) ? hh : (z == 1) ? wqh : (z == 2) ? wkh
                           : (z == 3) ? wvh : woh;
        unsigned short* lo = (z == 0) ? hl : (z == 1) ? wql : (z == 2) ? wkl
                           : (z == 3) ? wvl : wol;
        const int n4 = (z == 0) ? 1048576 : 262144;
        const int stride = gridDim.x * 256;
        for (int i = blockIdx.x * 256 + tid; i < n4; i += stride) {
            float4 x = *(const float4*)(src + i*4);
            unsigned short h[4], l[4];
            float xs[4] = {x.x, x.y, x.z, x.w};
            #pragma unroll
            for (int j = 0; j < 4; ++j) {
                h[j] = f2b(xs[j]);
                l[j] = f2b(xs[j] - bf16f(h[j]));
            }
            *(ushort4*)(hi + i*4) = make_ushort4(h[0], h[1], h[2], h[3]);
            *(ushort4*)(lo + i*4) = make_ushort4(l[0], l[1], l[2], l[3]);
        }
    } else if (blockIdx.x == 0) {
        for (int i = tid; i < 272*64; i += 256) {
            int j = i >> 6;
            relkB[i] = (j < 257) ? f2b(relk[i]) : (unsigned short)0;
        }
        int d = tid >> 2, grp = tid & 3;
        for (int jj = 0; jj < 66; ++jj) {
            int j = grp*66 + jj;
            if (j < 264)
                relvT[d*264 + j] = (j < 257) ? f2b(relv[j*64 + d]) : (unsigned short)0;
        }
    }
}

// ---------------------------------------------------------------------------
// K1: QKV projection, 128x64 tile, double-buffered async staging, 2-MFMA
// split (AhBh + AlBh).  Grid (16, 32, 3) = 1536 blocks, LDS 40 KB (4/CU).
// ---------------------------------------------------------------------------
__global__ __launch_bounds__(256) void k_gemm_qkv(
    const unsigned short* __restrict__ hh, const unsigned short* __restrict__ hl,
    const unsigned short* __restrict__ wqh, const unsigned short* __restrict__ wkh,
    const unsigned short* __restrict__ wvh,
    const float* __restrict__ bq, const float* __restrict__ bk,
    const float* __restrict__ bv,
    unsigned short* __restrict__ qb, unsigned short* __restrict__ kb,
    unsigned short* __restrict__ vt)
{
    __shared__ __align__(16) unsigned short sAh[2][128][32];
    __shared__ __align__(16) unsigned short sAl[2][128][32];
    __shared__ __align__(16) unsigned short sBh[2][64][32];
    const int tid = threadIdx.x;
    const int eb = blockIdx.x * 64, nb = blockIdx.y * 128, z = blockIdx.z;
    const unsigned short* Bh = (z == 0) ? wqh : (z == 1) ? wkh : wvh;
    const float* bias = (z == 0) ? bq : (z == 1) ? bk : bv;
    const float scale = (z == 0) ? 0.125f : 1.0f;
    const int w = tid >> 6, lane = tid & 63, lq = lane & 15, quad = lane >> 4;
    const int wr = w >> 1, wc = w & 1;

    // staging: lane l -> LDS slot (w*16 + l/4, l%4); global granule col
    // permuted so logical col c lands at physical (c+(row>>1))&3.
    const int prow = lane >> 2;
    const int pc8  = ((((lane & 3) - ((lane >> 3) & 3)) & 3)) * 8;
    const int arow = nb + w*16 + prow;
    const int brow = eb + w*16 + prow;

    f32x4 acc[4][2];
    #pragma unroll
    for (int i = 0; i < 4; ++i)
        #pragma unroll
        for (int j = 0; j < 2; ++j) acc[i][j] = (f32x4){0,0,0,0};

    const int pcol = ((quad + (lq >> 1)) & 3) * 8;   // swizzled frag column

    // prologue: stage tile 0 into buf 0
    {
        gl_lds16(hh + (size_t)arow * 1024 + pc8,        &sAh[0][w*16][0]);
        gl_lds16(hh + (size_t)(arow + 64) * 1024 + pc8, &sAh[0][64 + w*16][0]);
        gl_lds16(hl + (size_t)arow * 1024 + pc8,        &sAl[0][w*16][0]);
        gl_lds16(hl + (size_t)(arow + 64) * 1024 + pc8, &sAl[0][64 + w*16][0]);
        gl_lds16(Bh + (size_t)brow * 1024 + pc8,        &sBh[0][w*16][0]);
    }

    for (int k0 = 0; k0 < 1024; k0 += 32) {
        const int cur = (k0 >> 5) & 1;
        __syncthreads();   // buf[cur] loads drained; prev reads of buf[1-cur] done
        if (k0 < 992) {    // stage tile k+1 into the other buffer (flies during MFMA)
            const int kn = k0 + 32, nxt = 1 - cur;
            gl_lds16(hh + (size_t)arow * 1024 + kn + pc8,        &sAh[nxt][w*16][0]);
            gl_lds16(hh + (size_t)(arow + 64) * 1024 + kn + pc8, &sAh[nxt][64 + w*16][0]);
            gl_lds16(hl + (size_t)arow * 1024 + kn + pc8,        &sAl[nxt][w*16][0]);
            gl_lds16(hl + (size_t)(arow + 64) * 1024 + kn + pc8, &sAl[nxt][64 + w*16][0]);
            gl_lds16(Bh + (size_t)brow * 1024 + kn + pc8,        &sBh[nxt][w*16][0]);
        }

        short8 ah[4], al[4], bh2[2];
        #pragma unroll
        for (int t = 0; t < 4; ++t) {
            ah[t] = *(const short8*)&sAh[cur][wr*64 + t*16 + lq][pcol];
            al[t] = *(const short8*)&sAl[cur][wr*64 + t*16 + lq][pcol];
        }
        #pragma unroll
        for (int t = 0; t < 2; ++t)
            bh2[t] = *(const short8*)&sBh[cur][wc*32 + t*16 + lq][pcol];
        #pragma unroll
        for (int ti = 0; ti < 4; ++ti)
            #pragma unroll
            for (int tj = 0; tj < 2; ++tj) {
                acc[ti][tj] = __builtin_amdgcn_mfma_f32_16x16x32_bf16(ah[ti], bh2[tj], acc[ti][tj], 0, 0, 0);
                acc[ti][tj] = __builtin_amdgcn_mfma_f32_16x16x32_bf16(al[ti], bh2[tj], acc[ti][tj], 0, 0, 0);
            }
    }

    #pragma unroll
    for (int tj = 0; tj < 2; ++tj) {
        int e = eb + wc*32 + tj*16 + lq;
        float bb = bias[e];
        int h = e >> 6, d = e & 63;
        #pragma unroll
        for (int ti = 0; ti < 4; ++ti) {
            #pragma unroll
            for (int i = 0; i < 4; ++i) {
                int n = nb + wr*64 + ti*16 + quad*4 + i;
                int bidx = n >> 10, t = n & 1023;
                int s = bidx*16 + h;
                float val = (acc[ti][tj][i] + bb) * scale;
                if (z == 2)
                    vt[(((size_t)(s*64 + d)) << 10) + t] = f2b(val);
                else if (z == 0)
                    qb[(((size_t)(s*1024 + t)) << 6) + d] = f2b(val);
                else
                    kb[(((size_t)(s*1024 + t)) << 6) + d] = f2b(val);
            }
        }
    }
}

// ---------------------------------------------------------------------------
// K2: MFMA flash attention (unchanged from R14).
// ---------------------------------------------------------------------------
__global__ __launch_bounds__(256) void k_fused(
    const unsigned short* __restrict__ qb, const unsigned short* __restrict__ kb,
    const unsigned short* __restrict__ vt, const unsigned short* __restrict__ relkB,
    const unsigned short* __restrict__ relvT, const float* __restrict__ relv,
    float* __restrict__ c1, float* __restrict__ c2)
{
    __shared__ __align__(16) unsigned short sP[2][2][16][72];
    __shared__ __align__(16) unsigned short sG[2][16][104];
    __shared__ unsigned short sR[32][273];
    __shared__ float sRed[4][3][32];

    const int tid = threadIdx.x;
    const int m  = blockIdx.y;
    const int q0 = blockIdx.x * 32;
    const int pm = (m & 15) * 4 + (m >> 4);
    const int m2 = (m & 3) * 16 + (m >> 2);
    const int w    = tid >> 6;
    const int lane = tid & 63;
    const int lq   = lane & 15;
    const int quad = lane >> 4;

    #pragma unroll
    for (int sub = 0; sub < 2; ++sub) {
        const unsigned short* qpm = qb + (((size_t)(pm*1024 + q0 + sub*16 + lq)) << 6);
        short8 a0 = *(const short8*)(qpm + quad*8);
        short8 a1 = *(const short8*)(qpm + 32 + quad*8);
        for (int jt = w; jt < 17; jt += 4) {
            const unsigned short* rkb = relkB + (size_t)(jt*16 + lq) * 64;
            short8 b0 = *(const short8*)(rkb + quad*8);
            short8 b1 = *(const short8*)(rkb + 32 + quad*8);
            f32x4 cr = {0,0,0,0};
            cr = __builtin_amdgcn_mfma_f32_16x16x32_bf16(a0, b0, cr, 0, 0, 0);
            cr = __builtin_amdgcn_mfma_f32_16x16x32_bf16(a1, b1, cr, 0, 0, 0);
            #pragma unroll
            for (int i = 0; i < 4; ++i)
                sR[sub*16 + quad*4 + i][jt*16 + lq] = f2b(cr[i]);
        }
    }
    __syncthreads();

    short8 aq0[2], aq1[2];
    #pragma unroll
    for (int sub = 0; sub < 2; ++sub) {
        const unsigned short* qm = qb + (((size_t)(m*1024 + q0 + sub*16 + lq)) << 6);
        aq0[sub] = *(const short8*)(qm + quad*8);
        aq1[sub] = *(const short8*)(qm + 32 + quad*8);
    }
    const float relE0 = relv[w*16 + lq];
    const float relE1 = relv[256*64 + w*16 + lq];

    float lsum[2][4], slow[2][4], shigh[2][4];
    f32x4 c1a[2], c2a[2];
    #pragma unroll
    for (int sub = 0; sub < 2; ++sub) {
        c1a[sub] = (f32x4){0,0,0,0};
        c2a[sub] = (f32x4){0,0,0,0};
        #pragma unroll
        for (int i = 0; i < 4; ++i) {
            lsum[sub][i] = 0.0f; slow[sub][i] = 0.0f; shigh[sub][i] = 0.0f;
        }
    }

    const unsigned short* kbase = kb + (((size_t)(m*1024 + w*16 + lq)) << 6);
    const unsigned short* vbase = vt + (((size_t)(m*64 + w*16 + lq)) << 10);
    short8 ck0 = *(const short8*)(kbase + quad*8);
    short8 ck1 = *(const short8*)(kbase + 32 + quad*8);
    short8 cv0 = *(const short8*)(vbase + quad*8);
    short8 cv1 = *(const short8*)(vbase + 32 + quad*8);

    #pragma unroll 1
    for (int kt = 0; kt < 16; ++kt) {
        const int k0 = kt * 64;
        const int dmin = q0 - k0 - 63;
        const int dmax = q0 + 31 - k0;
        const bool needG = (dmax >= -127) && (dmin <= 127);
        const int buf = kt & 1;

        short8 nk0 = ck0, nk1 = ck1, nv0 = cv0, nv1 = cv1;
        if (kt < 15) {
            const size_t ko = (size_t)(k0 + 64);
            nk0 = *(const short8*)(kbase + (ko << 6) + quad*8);
            nk1 = *(const short8*)(kbase + (ko << 6) + 32 + quad*8);
            nv0 = *(const short8*)(vbase + ko + quad*8);
            nv1 = *(const short8*)(vbase + ko + 32 + quad*8);
        }

        f32x4 s4[2];
        #pragma unroll
        for (int sub = 0; sub < 2; ++sub) {
            s4[sub] = (f32x4){0,0,0,0};
            s4[sub] = __builtin_amdgcn_mfma_f32_16x16x32_bf16(aq0[sub], ck0, s4[sub], 0, 0, 0);
            s4[sub] = __builtin_amdgcn_mfma_f32_16x16x32_bf16(aq1[sub], ck1, s4[sub], 0, 0, 0);
        }

        const int kcol = k0 + w*16 + lq;
        float e[2][4];
        #pragma unroll
        for (int sub = 0; sub < 2; ++sub) {
            #pragma unroll
            for (int i = 0; i < 4; ++i) {
                int row = sub*16 + quad*4 + i;
                int dist = (q0 + row) - kcol;
                int jd = dist < -128 ? 0 : (dist > 128 ? 256 : dist + 128);
                float ev = exp2f((s4[sub][i] + bf16f(sR[row][jd])) * 1.44269504f);
                e[sub][i] = ev;
                lsum[sub][i] += ev;
                if (dist <= -128)     slow[sub][i]  += ev;
                else if (dist >= 128) shigh[sub][i] += ev;
                sP[buf][sub][quad*4 + i][w*16 + lq] = f2b(ev);
            }
        }
        if (needG) {
            #pragma unroll
            for (int i = 0; i < 7; ++i) {
                int idx = tid + i * 256;
                if (idx < 1664) ((unsigned int*)sG)[idx] = 0u;
            }
        }
        __syncthreads();

        if (needG) {
            #pragma unroll
            for (int sub = 0; sub < 2; ++sub) {
                int jminb = q0 + sub*16 - k0 - 63;
                jminb = (jminb < -127 ? -127 : jminb) + 128;
                int jlo8 = jminb & ~7;
                if (jlo8 > 160) jlo8 = 160;
                #pragma unroll
                for (int i = 0; i < 4; ++i) {
                    int row = sub*16 + quad*4 + i;
                    int dist = (q0 + row) - kcol;
                    if (dist > -128 && dist < 128)
                        sG[sub][quad*4 + i][dist + 128 - jlo8] = f2b(e[sub][i]);
                }
            }
        }

        #pragma unroll
        for (int sub = 0; sub < 2; ++sub) {
            short8 ap0 = *(const short8*)&sP[buf][sub][lq][quad*8];
            short8 ap1 = *(const short8*)&sP[buf][sub][lq][32 + quad*8];
            c1a[sub] = __builtin_amdgcn_mfma_f32_16x16x32_bf16(ap0, cv0, c1a[sub], 0, 0, 0);
            c1a[sub] = __builtin_amdgcn_mfma_f32_16x16x32_bf16(ap1, cv1, c1a[sub], 0, 0, 0);
        }

        if (needG) {
            __syncthreads();
            #pragma unroll
            for (int sub = 0; sub < 2; ++sub) {
                int jminb = q0 + sub*16 - k0 - 63;
                jminb = (jminb < -127 ? -127 : jminb) + 128;
                int jlo8 = jminb & ~7;
                if (jlo8 > 160) jlo8 = 160;
                short8 ag0 = *(const short8*)&sG[sub][lq][quad*8];
                short8 ag1 = *(const short8*)&sG[sub][lq][32 + quad*8];
                short8 ag2 = *(const short8*)&sG[sub][lq][64 + quad*8];
                const unsigned short* rrow = relvT + (size_t)(w*16 + lq) * 264 + jlo8;
                short8 br0 = *(const short8*)(rrow + quad*8);
                short8 br1 = *(const short8*)(rrow + 32 + quad*8);
                short8 br2 = *(const short8*)(rrow + 64 + quad*8);
                c2a[sub] = __builtin_amdgcn_mfma_f32_16x16x32_bf16(ag0, br0, c2a[sub], 0, 0, 0);
                c2a[sub] = __builtin_amdgcn_mfma_f32_16x16x32_bf16(ag1, br1, c2a[sub], 0, 0, 0);
                c2a[sub] = __builtin_amdgcn_mfma_f32_16x16x32_bf16(ag2, br2, c2a[sub], 0, 0, 0);
            }
            __syncthreads();
        }

        ck0 = nk0; ck1 = nk1; cv0 = nv0; cv1 = nv1;
    }

    #pragma unroll
    for (int off = 1; off < 16; off <<= 1) {
        #pragma unroll
        for (int sub = 0; sub < 2; ++sub)
            #pragma unroll
            for (int i = 0; i < 4; ++i) {
                lsum[sub][i]  += __shfl_xor(lsum[sub][i],  off, 64);
                slow[sub][i]  += __shfl_xor(slow[sub][i],  off, 64);
                shigh[sub][i] += __shfl_xor(shigh[sub][i], off, 64);
            }
    }
    if (lq == 0) {
        #pragma unroll
        for (int sub = 0; sub < 2; ++sub)
            #pragma unroll
            for (int i = 0; i < 4; ++i) {
                int row = sub*16 + quad*4 + i;
                sRed[w][0][row] = lsum[sub][i];
                sRed[w][1][row] = slow[sub][i];
                sRed[w][2][row] = shigh[sub][i];
            }
    }
    __syncthreads();

    const int b1 = m >> 4,  h1 = m & 15;
    const int b2 = m2 >> 4, h2 = m2 & 15;
    #pragma unroll
    for (int sub = 0; sub < 2; ++sub) {
        #pragma unroll
        for (int i = 0; i < 4; ++i) {
            int row = sub*16 + quad*4 + i;
            float lt = sRed[0][0][row] + sRed[1][0][row] + sRed[2][0][row] + sRed[3][0][row];
            float sl = sRed[0][1][row] + sRed[1][1][row] + sRed[2][1][row] + sRed[3][1][row];
            float sh = sRed[0][2][row] + sRed[1][2][row] + sRed[2][2][row] + sRed[3][2][row];
            float c2v = c2a[sub][i] + sl * relE0 + sh * relE1;
            float inv = 1.0f / lt;
            int col = w*16 + lq;
            c1[(size_t)(b1*1024 + q0 + row) * 1024 + h1*64 + col] = c1a[sub][i] * inv;
            c2[(size_t)(b2*1024 + q0 + row) * 1024 + h2*64 + col] = c2v * inv;
        }
    }
}

// ---------------------------------------------------------------------------
// K3: out = (c1+c2) @ Wo^T + bo, 128x64 tile, swizzled LDS; A split on the
// fly (sync staging), B via global_load_lds.  (unchanged from R14)
// ---------------------------------------------------------------------------
__global__ __launch_bounds__(256) void k_gemm_o(
    const float* __restrict__ c1, const float* __restrict__ c2,
    const unsigned short* __restrict__ woh, const unsigned short* __restrict__ wol,
    const float* __restrict__ bo, float* __restrict__ outp)
{
    __shared__ __align__(16) unsigned short sAh[128][32];
    __shared__ __align__(16) unsigned short sAl[128][32];
    __shared__ __align__(16) unsigned short sBh[64][32];
    __shared__ __align__(16) unsigned short sBl[64][32];
    const int tid = threadIdx.x;
    const int eb = blockIdx.x * 64, nb = blockIdx.y * 128;
    const int w = tid >> 6, lane = tid & 63, lq = lane & 15, quad = lane >> 4;
    const int wr = w >> 1, wc = w & 1;

    const int ar0 = tid >> 2, ac = tid & 3;
    const int swc = (((tid & 3) + ((tid >> 3) & 3)) & 3) * 8;
    const int prow = lane >> 2;
    const int pc8  = ((((lane & 3) - ((lane >> 3) & 3)) & 3)) * 8;
    unsigned short* dBh0 = &sBh[w*16][0];
    unsigned short* dBl0 = &sBl[w*16][0];
    const int brow = eb + w*16 + prow;

    f32x4 acc[4][2];
    #pragma unroll
    for (int i = 0; i < 4; ++i)
        #pragma unroll
        for (int j = 0; j < 2; ++j) acc[i][j] = (f32x4){0,0,0,0};

    const int pcol = ((quad + (lq >> 1)) & 3) * 8;

    for (int k0 = 0; k0 < 1024; k0 += 32) {
        size_t o0 = (size_t)(nb + ar0) * 1024 + k0 + ac*8;
        size_t o1 = (size_t)(nb + ar0 + 64) * 1024 + k0 + ac*8;
        float4 x0 = *(const float4*)(c1 + o0), x1 = *(const float4*)(c1 + o0 + 4);
        float4 y0 = *(const float4*)(c2 + o0), y1 = *(const float4*)(c2 + o0 + 4);
        float4 X0 = *(const float4*)(c1 + o1), X1 = *(const float4*)(c1 + o1 + 4);
        float4 Y0 = *(const float4*)(c2 + o1), Y1 = *(const float4*)(c2 + o1 + 4);
        __syncthreads();
        gl_lds16(woh + (size_t)brow * 1024 + k0 + pc8, dBh0);
        gl_lds16(wol + (size_t)brow * 1024 + k0 + pc8, dBl0);
        {
            float a0[8] = {x0.x+y0.x, x0.y+y0.y, x0.z+y0.z, x0.w+y0.w,
                           x1.x+y1.x, x1.y+y1.y, x1.z+y1.z, x1.w+y1.w};
            float a1[8] = {X0.x+Y0.x, X0.y+Y0.y, X0.z+Y0.z, X0.w+Y0.w,
                           X1.x+Y1.x, X1.y+Y1.y, X1.z+Y1.z, X1.w+Y1.w};
            unsigned short h8[8], l8[8], H8[8], L8[8];
            #pragma unroll
            for (int j = 0; j < 8; ++j) {
                h8[j] = f2b(a0[j]);  l8[j] = f2b(a0[j] - bf16f(h8[j]));
                H8[j] = f2b(a1[j]);  L8[j] = f2b(a1[j] - bf16f(H8[j]));
            }
            *(uint4*)&sAh[ar0][swc]      = *(const uint4*)h8;
            *(uint4*)&sAl[ar0][swc]      = *(const uint4*)l8;
            *(uint4*)&sAh[ar0 + 64][swc] = *(const uint4*)H8;
            *(uint4*)&sAl[ar0 + 64][swc] = *(const uint4*)L8;
        }
        __syncthreads();

        short8 ah[4], al[4], bhf[2], blf[2];
        #pragma unroll
        for (int t = 0; t < 4; ++t) {
            ah[t] = *(const short8*)&sAh[wr*64 + t*16 + lq][pcol];
            al[t] = *(const short8*)&sAl[wr*64 + t*16 + lq][pcol];
        }
        #pragma unroll
        for (int t = 0; t < 2; ++t) {
            bhf[t] = *(const short8*)&sBh[wc*32 + t*16 + lq][pcol];
            blf[t] = *(const short8*)&sBl[wc*32 + t*16 + lq][pcol];
        }
        #pragma unroll
        for (int ti = 0; ti < 4; ++ti)
            #pragma unroll
            for (int tj = 0; tj < 2; ++tj) {
                acc[ti][tj] = __builtin_amdgcn_mfma_f32_16x16x32_bf16(ah[ti], bhf[tj], acc[ti][tj], 0, 0, 0);
                acc[ti][tj] = __builtin_amdgcn_mfma_f32_16x16x32_bf16(al[ti], bhf[tj], acc[ti][tj], 0, 0, 0);
                acc[ti][tj] = __builtin_amdgcn_mfma_f32_16x16x32_bf16(ah[ti], blf[tj], acc[ti][tj], 0, 0, 0);
            }
    }

    #pragma unroll
    for (int tj = 0; tj < 2; ++tj) {
        int e = eb + wc*32 + tj*16 + lq;
        float bb = bo[e];
        #pragma unroll
        for (int ti = 0; ti < 4; ++ti) {
            #pragma unroll
            for (int i = 0; i < 4; ++i) {
                int n = nb + wr*64 + ti*16 + quad*4 + i;
                outp[(size_t)n * 1024 + e] = acc[ti][tj][i] + bb;
            }
        }
    }
}

// ---------------------------------------------------------------------------
extern "C" void kernel_launch(void* const* d_in, const int* in_sizes, int n_in,
                              void* d_out, int out_size, void* d_ws, size_t ws_size,
                              hipStream_t stream) {
    const float* hs   = (const float*)d_in[0];
    const float* Wq   = (const float*)d_in[1];
    const float* bq   = (const float*)d_in[2];
    const float* Wk   = (const float*)d_in[3];
    const float* bk   = (const float*)d_in[4];
    const float* Wv   = (const float*)d_in[5];
    const float* bv   = (const float*)d_in[6];
    const float* Wo   = (const float*)d_in[7];
    const float* bo   = (const float*)d_in[8];
    const float* relk = (const float*)d_in[9];
    const float* relv = (const float*)d_in[10];
    float* out = (float*)d_out;

    unsigned short* wsu = (unsigned short*)d_ws;
    unsigned short* qbp   = wsu;
    unsigned short* kbp   = wsu + 4194304;
    unsigned short* vtp   = wsu + 8388608;
    unsigned short* relkB = wsu + 12582912;
    unsigned short* relvT = wsu + 12600320;
    float* c1 = (float*)(wsu + 12617360);
    float* c2 = c1 + 4194304;
    unsigned short* hh  = wsu + 29394576;
    unsigned short* hl  = hh + 4194304;
    unsigned short* wqh = hl + 4194304;
    unsigned short* wql = wqh + 1048576;
    unsigned short* wkh = wql + 1048576;
    unsigned short* wkl = wkh + 1048576;
    unsigned short* wvh = wkl + 1048576;
    unsigned short* wvl = wvh + 1048576;
    unsigned short* woh = wvl + 1048576;
    unsigned short* wol = woh + 1048576;

    k_prep<<<dim3(512, 6), 256, 0, stream>>>(hs, Wq, Wk, Wv, Wo, relk, relv,
                                             hh, hl, wqh, wql, wkh, wkl,
                                             wvh, wvl, woh, wol, relkB, relvT);
    k_gemm_qkv<<<dim3(16, 32, 3), 256, 0, stream>>>(hh, hl, wqh, wkh, wvh,
                                                    bq, bk, bv, qbp, kbp, vtp);
    k_fused<<<dim3(32, 64), 256, 0, stream>>>(qbp, kbp, vtp, relkB, relvT, relv, c1, c2);
    k_gemm_o<<<dim3(16, 32), 256, 0, stream>>>(c1, c2, woh, wol, bo, out);
}